// Round 3
// baseline (10651.981 us; speedup 1.0000x reference)
//
#include <hip/hip_runtime.h>
#include <hip/hip_bf16.h>

typedef __hip_bfloat16 bf16;

constexpr int Hn = 64, Wn = 64, Cm = 96, Ln = 4096;
constexpr int Di = 192, Kn = 4, Ns = 16, Rr = 6;

static __device__ __forceinline__ float ldv(const float* p, long i){ return p[i]; }
static __device__ __forceinline__ float ldv(const bf16*  p, long i){ return __bfloat162float(p[i]); }
static __device__ __forceinline__ void  stv(float* p, long i, float v){ p[i] = v; }
static __device__ __forceinline__ void  stv(bf16*  p, long i, float v){ p[i] = __float2bfloat16(v); }

// ------------------------------------------------ dtype detector (f32 vs bf16)
__global__ void k_detect(const unsigned short* x, int* flag){
  __shared__ int cnt;
  if (threadIdx.x == 0) cnt = 0;
  __syncthreads();
  int local = 0;
  for (int i = threadIdx.x; i < 8192; i += 256){
    int e = (x[i] >> 7) & 0xFF;                 // bf16 exponent field
    if (e != 0 && (e < 90 || e > 164)) local++; // impossible for N(0,1) bf16
  }
  atomicAdd(&cnt, local);
  __syncthreads();
  if (threadIdx.x == 0) *flag = (cnt > 400) ? 1 : 0;   // 1 => float32 data
}

// ---------------------------------------------------------------- in_proj GEMM
template<typename T>
__device__ void inproj_body(const T* x, long xoff, const T* w, T* Xb, T* Z, float* xs){
  const T* xp = x + xoff;
  int c = threadIdx.x;
  long p0 = (long)blockIdx.x * 8;
  for (int i = c; i < 8*96; i += 384) xs[i] = ldv(xp, p0*96 + i);
  __syncthreads();
  float acc[8] = {0,0,0,0,0,0,0,0};
  for (int kk = 0; kk < 96; ++kk){
    float wv = ldv(w, (long)c*96 + kk);
    #pragma unroll
    for (int p = 0; p < 8; ++p) acc[p] += wv * xs[p*96 + kk];
  }
  if (c < Di){
    #pragma unroll
    for (int p = 0; p < 8; ++p) stv(Xb, (p0+p)*Di + c, acc[p]);
  } else {
    int c2 = c - Di;
    #pragma unroll
    for (int p = 0; p < 8; ++p) stv(Z, (p0+p)*Di + c2, acc[p]);
  }
}
__global__ __launch_bounds__(384) void k_inproj(const void* x, long xoff, const void* w,
                                                void* Xb, void* Z, const int* flag){
  __shared__ float xs[8*96];
  if (*flag) inproj_body<float>((const float*)x, xoff, (const float*)w, (float*)Xb, (float*)Z, xs);
  else       inproj_body<bf16 >((const bf16* )x, xoff, (const bf16* )w, (bf16* )Xb, (bf16* )Z, xs);
}

// ---------------------------------------------------- depthwise conv3x3 + SiLU
template<typename T>
__device__ void conv_body(const T* Xb, const T* cw, const T* cb, T* xc, float* wle){
  float* ble = wle + Di*9;
  int h = blockIdx.x;
  for (int i = threadIdx.x; i < Di*9; i += 256) wle[i] = ldv(cw, i);
  for (int i = threadIdx.x; i < Di;   i += 256) ble[i] = ldv(cb, i);
  __syncthreads();
  for (int idx = threadIdx.x; idx < Di*Wn; idx += 256){
    int d = idx >> 6, wcol = idx & 63;
    float acc = ble[d];
    #pragma unroll
    for (int dh = -1; dh <= 1; ++dh){
      int hh = h + dh; if (hh < 0 || hh > 63) continue;
      #pragma unroll
      for (int dw = -1; dw <= 1; ++dw){
        int ww = wcol + dw; if (ww < 0 || ww > 63) continue;
        acc += wle[d*9 + (dh+1)*3 + (dw+1)] * ldv(Xb, (long)(hh*64+ww)*Di + d);
      }
    }
    float sv = acc / (1.f + __expf(-acc));
    stv(xc, (long)d*Ln + h*64 + wcol, sv);
  }
}
__global__ __launch_bounds__(256) void k_conv(const void* Xb, const void* cw, const void* cb,
                                              void* xc, const int* flag){
  __shared__ float wle[Di*9 + Di];
  if (*flag) conv_body<float>((const float*)Xb, (const float*)cw, (const float*)cb, (float*)xc, wle);
  else       conv_body<bf16 >((const bf16* )Xb, (const bf16* )cw, (const bf16* )cb, (bf16* )xc, wle);
}

// ------------------------------------------------------- 64x64 tile transpose
template<typename T>
__device__ void transpose_body(const T* xc, T* xcT, float* t){
  long bd = blockIdx.x;
  const T* src = xc + bd*Ln;
  T* dst = xcT + bd*Ln;
  for (int i = threadIdx.x; i < 4096; i += 256) t[(i>>6)*65 + (i&63)] = ldv(src, i);
  __syncthreads();
  for (int i = threadIdx.x; i < 4096; i += 256){
    int wq = i >> 6, hq = i & 63;
    stv(dst, i, t[hq*65 + wq]);
  }
}
__global__ __launch_bounds__(256) void k_transpose(const void* xc, void* xcT, const int* flag){
  __shared__ float t[64*65];
  if (*flag) transpose_body<float>((const float*)xc, (float*)xcT, t);
  else       transpose_body<bf16 >((const bf16* )xc, (bf16* )xcT, t);
}

// --------------------------------------------- x_proj (dts/Bs/Cs, scan order)
template<typename T>
__device__ void proj_body(const T* xc, const T* xcT, const T* xpw,
                          T* dts, T* Bsb, T* Csb, float* xt){
  int blk = blockIdx.x;
  int tile = blk & 127; int s = (blk >> 7) & 1;
  int q0 = tile * 32;
  const T* src = s ? xcT : xc;
  for (int i = threadIdx.x; i < Di*32; i += 256){
    int d = i >> 5, j = i & 31;
    xt[d*33 + j] = ldv(src, (long)d*Ln + q0 + j);
  }
  __syncthreads();
  for (int o = threadIdx.x; o < 2*38*32; o += 256){
    int j = o & 31; int c = (o >> 5) % 38; int kk = o / (38*32);
    int k = s + 2*kk;
    float acc = 0.f;
    for (int d2 = 0; d2 < Di; ++d2)
      acc += ldv(xpw, ((long)k*38 + c)*Di + d2) * xt[d2*33 + j];
    int q = q0 + j;
    int l = kk ? (Ln-1-q) : q;
    long base = (long)k*Ln + l;
    if (c < 6)       stv(dts, base*6  + c,      acc);
    else if (c < 22) stv(Bsb, base*16 + (c-6),  acc);
    else             stv(Csb, base*16 + (c-22), acc);
  }
}
__global__ __launch_bounds__(256) void k_proj(const void* xc, const void* xcT, const void* xpw,
                                              void* dts, void* Bs, void* Cs, const int* flag){
  __shared__ float xt[Di*33];
  if (*flag) proj_body<float>((const float*)xc, (const float*)xcT, (const float*)xpw,
                              (float*)dts, (float*)Bs, (float*)Cs, xt);
  else       proj_body<bf16 >((const bf16* )xc, (const bf16* )xcT, (const bf16* )xpw,
                              (bf16* )dts, (bf16* )Bs, (bf16* )Cs, xt);
}

// ------------------------------------------------------------- selective scan
template<typename T>
__device__ void scan_body(const T* xc, const T* xcT, const T* dts, const T* Bsb, const T* Csb,
                          const T* Alog, const T* dtw, const T* dtb, const T* Dsv,
                          T* ys, float* sm){
  float* lu   = sm;            // 16*65
  float* ldt  = lu  + 1040;    // 16*65
  float* lB   = ldt + 1040;    // 64*16
  float* lC   = lB  + 1024;    // 64*16
  float* ly   = lC  + 1024;    // 16*65
  float* ldtw = ly  + 1040;    // 16*6
  float* ldtb = ldtw + 96;     // 16
  float* ldsv = ldtb + 16;     // 16
  int blk = blockIdx.x;
  int dgrp = blk % 12; int k = blk / 12;
  int d0 = dgrp * 16;
  int tid = threadIdx.x;
  int dl_ = tid >> 4, n = tid & 15;
  int d = d0 + dl_;
  bool rev = (k >= 2);
  const T* src = ((k & 1) ? xcT : xc) + (long)d0*Ln;
  long pb = (long)k*Ln;
  const T* dtsb = dts + pb*6;
  const T* Bb = Bsb + pb*16;
  const T* Cb = Csb + pb*16;
  T* yb = ys + pb*Di;

  if (tid < 16){
    ldtb[tid] = ldv(dtb, k*Di + d0 + tid);
    ldsv[tid] = ldv(Dsv, k*Di + d0 + tid);
  }
  if (tid < 96){
    int dd = tid / 6, r = tid % 6;
    ldtw[dd*6 + r] = ldv(dtw, ((long)k*Di + d0 + dd)*6 + r);
  }
  float a = -__expf(ldv(Alog, d*16 + n));
  float h = 0.f;
  __syncthreads();

  for (int tile = 0; tile < 64; ++tile){
    int l0 = tile * 64;
    for (int i = tid; i < 16*64; i += 256){
      int dd = i >> 6, j = i & 63;
      int l = l0 + j;
      int pos = rev ? (Ln-1-l) : l;
      lu[dd*65 + j] = ldv(src, (long)dd*Ln + pos);
    }
    for (int i = tid; i < 64*16; i += 256){
      lB[i] = ldv(Bb, (long)l0*16 + i);
      lC[i] = ldv(Cb, (long)l0*16 + i);
    }
    for (int i = tid; i < 16*64; i += 256){
      int dd = i >> 6, j = i & 63;
      float xv = ldtb[dd];
      #pragma unroll
      for (int r = 0; r < 6; ++r) xv += ldtw[dd*6 + r] * ldv(dtsb, (long)(l0+j)*6 + r);
      ldt[dd*65 + j] = (xv > 15.f) ? xv : log1pf(__expf(xv));
    }
    __syncthreads();
    for (int j = 0; j < 64; ++j){
      float dl = ldt[dl_*65 + j];
      float ul = lu[dl_*65 + j];
      float bb = lB[j*16 + n], cc = lC[j*16 + n];
      h = __expf(dl * a) * h + (dl * ul) * bb;
      float yv = h * cc;
      yv += __shfl_xor(yv, 1);
      yv += __shfl_xor(yv, 2);
      yv += __shfl_xor(yv, 4);
      yv += __shfl_xor(yv, 8);
      if (n == 0) ly[dl_*65 + j] = yv + ldsv[dl_] * ul;
    }
    __syncthreads();
    for (int i = tid; i < 16*64; i += 256){
      int j = i >> 4, dd = i & 15;
      int l = l0 + j;
      int pos = rev ? (Ln-1-l) : l;
      stv(yb, (long)pos*Di + d0 + dd, ly[dd*65 + j]);
    }
    __syncthreads();
  }
}
__global__ __launch_bounds__(256) void k_scan(const void* xc, const void* xcT, const void* dts,
                                              const void* Bs, const void* Cs, const void* Alog,
                                              const void* dtw, const void* dtb, const void* Dsv,
                                              void* ys, const int* flag){
  __shared__ float sm[5296];
  if (*flag) scan_body<float>((const float*)xc,(const float*)xcT,(const float*)dts,
                              (const float*)Bs,(const float*)Cs,(const float*)Alog,
                              (const float*)dtw,(const float*)dtb,(const float*)Dsv,(float*)ys,sm);
  else       scan_body<bf16 >((const bf16* )xc,(const bf16* )xcT,(const bf16* )dts,
                              (const bf16* )Bs,(const bf16* )Cs,(const bf16* )Alog,
                              (const bf16* )dtw,(const bf16* )dtb,(const bf16* )Dsv,(bf16* )ys,sm);
}

// ---------------------- CrossMerge + LayerNorm + gate + out_proj (fused)
template<typename T>
__device__ void out_body(const T* ys, const T* Z, const T* lnw, const T* lnb,
                         const T* wo, T* out, long ooff, float* ty){
  int h = blockIdx.x;
  for (int i = threadIdx.x; i < 64*Di; i += 256){
    int j = i / Di, d = i % Di;
    long ls = (long)(h*64 + j)*Di + d;   // spatial order (planes 0,2)
    long lt = (long)(j*64 + h)*Di + d;   // transposed order (planes 1,3)
    ty[d*65 + j] = ldv(ys, (long)(0*Ln)*Di + ls) + ldv(ys, (long)(2*Ln)*Di + ls)
                 + ldv(ys, (long)(1*Ln)*Di + lt) + ldv(ys, (long)(3*Ln)*Di + lt);
  }
  __syncthreads();
  int jj = threadIdx.x >> 2, part = threadIdx.x & 3;
  float s = 0.f, s2 = 0.f;
  for (int c = part*48; c < part*48+48; ++c){
    float v = ty[c*65 + jj]; s += v; s2 += v*v;
  }
  s += __shfl_xor(s, 1); s2 += __shfl_xor(s2, 1);
  s += __shfl_xor(s, 2); s2 += __shfl_xor(s2, 2);
  float mu = s * (1.f/192.f);
  float var = s2 * (1.f/192.f) - mu*mu;
  float rstd = rsqrtf(fmaxf(var, 0.f) + 1e-5f);
  long zbase = ((long)h*64 + jj)*Di;
  for (int c = part*48; c < part*48+48; ++c){
    float zv = ldv(Z, zbase + c);
    float g = zv / (1.f + __expf(-zv));
    float yn = (ty[c*65 + jj] - mu) * rstd * ldv(lnw, c) + ldv(lnb, c);
    ty[c*65 + jj] = yn * g;
  }
  __syncthreads();
  T* ob = out + ooff + ((long)h*64 + jj)*Cm;
  for (int o = part; o < Cm; o += 4){
    float acc = 0.f;
    for (int c = 0; c < Di; ++c) acc += ldv(wo, (long)o*Di + c) * ty[c*65 + jj];
    stv(ob, o, acc);
  }
}
__global__ __launch_bounds__(256) void k_out(const void* ys, const void* Z, const void* lnw,
                                             const void* lnb, const void* wo, void* out,
                                             long ooff, const int* flag){
  __shared__ float ty[Di*65];
  if (*flag) out_body<float>((const float*)ys,(const float*)Z,(const float*)lnw,
                             (const float*)lnb,(const float*)wo,(float*)out,ooff,ty);
  else       out_body<bf16 >((const bf16* )ys,(const bf16* )Z,(const bf16* )lnw,
                             (const bf16* )lnb,(const bf16* )wo,(bf16* )out,ooff,ty);
}

extern "C" void kernel_launch(void* const* d_in, const int* in_sizes, int n_in,
                              void* d_out, int out_size, void* d_ws, size_t ws_size,
                              hipStream_t stream){
  const void* x    = d_in[0];
  const void* ipw  = d_in[1];
  const void* cw   = d_in[2];
  const void* cb   = d_in[3];
  const void* xpw  = d_in[4];
  const void* dtw  = d_in[5];
  const void* dtb  = d_in[6];
  const void* Alog = d_in[7];
  const void* Dsv  = d_in[8];
  const void* lnw  = d_in[9];
  const void* lnb  = d_in[10];
  const void* wo   = d_in[11];

  // Workspace: byte offsets sized for the f32 (worst) case. Peak 25.2 MB.
  char* base = (char*)d_ws;
  int*  flag = (int*)base;
  size_t off = 256;
  const size_t PL = (size_t)Ln*Di*4;        // one (D,L) plane, f32 bytes
  void* Z   = base + off;  off += PL;
  void* xc  = base + off;  off += PL;
  void* xcT = base + off;  off += PL;
  void* Xb  = base + off;  off += PL;       // aliased by dts/Bs/Cs after conv
  void* ys  = base + off;  off += (size_t)Kn*Ln*Di*4;
  char* dts = (char*)Xb;
  char* Bs  = dts + (size_t)Kn*Ln*6*4;
  char* Cs  = Bs  + (size_t)Kn*Ln*16*4;

  k_detect<<<1, 256, 0, stream>>>((const unsigned short*)x, flag);

  for (int ch = 0; ch < 8; ++ch){
    long xoff = (long)ch*Ln*Cm;             // element offset
    k_inproj   <<<Ln/8,       384, 0, stream>>>(x, xoff, ipw, Xb, Z, flag);
    k_conv     <<<Hn,         256, 0, stream>>>(Xb, cw, cb, xc, flag);
    k_transpose<<<Di,         256, 0, stream>>>(xc, xcT, flag);
    k_proj     <<<2*(Ln/32),  256, 0, stream>>>(xc, xcT, xpw, dts, Bs, Cs, flag);
    k_scan     <<<Kn*12,      256, 0, stream>>>(xc, xcT, dts, Bs, Cs,
                                                Alog, dtw, dtb, Dsv, ys, flag);
    k_out      <<<Hn,         256, 0, stream>>>(ys, Z, lnw, lnb, wo, d_out, xoff, flag);
  }
}

// Round 4
// 1788.960 us; speedup vs baseline: 5.9543x; 5.9543x over previous
//
#include <hip/hip_runtime.h>
#include <hip/hip_bf16.h>

typedef __hip_bfloat16 bf16;
typedef unsigned short u16;
typedef unsigned int   u32;

constexpr int Hn=64, Wn=64, Cm=96, Ln=4096, Di=192, Kn=4, Ns=16, Rr=6;

static __device__ __forceinline__ float ldv(const float* p, long i){ return p[i]; }
static __device__ __forceinline__ float ldv(const bf16*  p, long i){ return __bfloat162float(p[i]); }
static __device__ __forceinline__ void  stv(float* p, long i, float v){ p[i] = v; }
static __device__ __forceinline__ void  stv(bf16*  p, long i, float v){ p[i] = __float2bfloat16(v); }
static __device__ __forceinline__ float bfr(u16 u){ return __uint_as_float((u32)u << 16); }
static __device__ __forceinline__ u16   fbr(float f){ bf16 h = __float2bfloat16(f); return *(u16*)&h; }
static __device__ __forceinline__ float4 ldv4(const float* p, long i){ return *(const float4*)(p + i); }
static __device__ __forceinline__ float4 ldv4(const bf16* p, long i){
  ushort4 u = *(const ushort4*)(p + i);
  return make_float4(bfr(u.x), bfr(u.y), bfr(u.z), bfr(u.w));
}
static __device__ __forceinline__ float splus(float x){ return (x > 15.f) ? x : log1pf(__expf(x)); }

// ------------------------------------------------ dtype detector (f32 vs bf16)
__global__ void k_detect(const u16* x, int* flag){
  __shared__ int cnt;
  if (threadIdx.x == 0) cnt = 0;
  __syncthreads();
  int local = 0;
  for (int i = threadIdx.x; i < 8192; i += 256){
    int e = (x[i] >> 7) & 0xFF;
    if (e != 0 && (e < 90 || e > 164)) local++;
  }
  atomicAdd(&cnt, local);
  __syncthreads();
  if (threadIdx.x == 0) *flag = (cnt > 400) ? 1 : 0;   // 1 => float32 inputs
}

// ---------------------------------------------------------------- in_proj GEMM
template<typename T>
__device__ void inproj_body(const T* x, const T* w, u16* Xb, u16* Z){
  __shared__ float xs[8*96];
  int c = threadIdx.x;
  long p0 = (long)blockIdx.x * 8;
  for (int i = c; i < 768; i += 384) xs[i] = ldv(x, p0*96 + i);
  __syncthreads();
  float acc[8] = {0,0,0,0,0,0,0,0};
  for (int kk = 0; kk < 96; kk += 4){
    float4 wv = ldv4(w, (long)c*96 + kk);
    #pragma unroll
    for (int p = 0; p < 8; ++p)
      acc[p] += wv.x*xs[p*96+kk] + wv.y*xs[p*96+kk+1]
              + wv.z*xs[p*96+kk+2] + wv.w*xs[p*96+kk+3];
  }
  if (c < Di){
    #pragma unroll
    for (int p = 0; p < 8; ++p) Xb[(p0+p)*Di + c] = fbr(acc[p]);
  } else {
    int c2 = c - Di;
    #pragma unroll
    for (int p = 0; p < 8; ++p) Z[(p0+p)*Di + c2] = fbr(acc[p]);
  }
}
__global__ __launch_bounds__(384) void k_inproj(const void* x, long xoff, const void* w,
                                                u16* Xb, u16* Z, const int* flag){
  if (*flag) inproj_body<float>((const float*)x + xoff, (const float*)w, Xb, Z);
  else       inproj_body<bf16 >((const bf16* )x + xoff, (const bf16* )w, Xb, Z);
}

// ---------------------------------------------------- depthwise conv3x3 + SiLU
template<typename T>
__device__ void conv_body(const u16* Xb, const T* cw, const T* cb, u16* xc, float* wle, u16* tl){
  float* ble = wle + Di*9;
  int b = blockIdx.x >> 6, h = blockIdx.x & 63;
  for (int i = threadIdx.x; i < Di*9; i += 256) wle[i] = ldv(cw, i);
  for (int i = threadIdx.x; i < Di;   i += 256) ble[i] = ldv(cb, i);
  __syncthreads();
  const u16* Xbb = Xb + (long)b*Ln*Di;
  u16* xcb = xc + (long)b*Di*Ln;
  for (int i = threadIdx.x; i < Di*Wn; i += 256){
    int w = i / 192, d = i % 192;      // lanes d-consecutive -> coalesced reads
    float acc = ble[d];
    #pragma unroll
    for (int dh = -1; dh <= 1; ++dh){
      int hh = h + dh; if (hh < 0 || hh > 63) continue;
      #pragma unroll
      for (int dw = -1; dw <= 1; ++dw){
        int ww = w + dw; if (ww < 0 || ww > 63) continue;
        acc += wle[d*9 + (dh+1)*3 + (dw+1)] * bfr(Xbb[(long)(hh*64+ww)*Di + d]);
      }
    }
    float sv = acc / (1.f + __expf(-acc));
    tl[d*66 + w] = fbr(sv);            // 66-pad: conflict-free d-major writes
  }
  __syncthreads();
  for (int i = threadIdx.x; i < Di*Wn; i += 256){
    int d = i >> 6, w = i & 63;
    xcb[(long)d*Ln + h*64 + w] = tl[d*66 + w];
  }
}
__global__ __launch_bounds__(256) void k_conv(const u16* Xb, const void* cw, const void* cb,
                                              u16* xc, const int* flag){
  __shared__ float wle[Di*9 + Di];
  __shared__ u16 tl[Di*66];
  if (*flag) conv_body<float>(Xb, (const float*)cw, (const float*)cb, xc, wle, tl);
  else       conv_body<bf16 >(Xb, (const bf16* )cw, (const bf16* )cb, xc, wle, tl);
}

// ------------------------------------------------------- 64x64 tile transpose
__global__ __launch_bounds__(256) void k_transpose(const u16* xc, u16* xcT){
  long bd = blockIdx.x;
  const u16* src = xc + bd*Ln;
  u16* dst = xcT + bd*Ln;
  __shared__ u16 tl[64*65];
  for (int i = threadIdx.x; i < 4096; i += 256) tl[(i>>6)*65 + (i&63)] = src[i];
  __syncthreads();
  for (int i = threadIdx.x; i < 4096; i += 256){
    int wq = i >> 6, hq = i & 63;
    dst[i] = tl[hq*65 + wq];
  }
}

// --------------------------------------------- x_proj (dts + packed B/C, scan order)
template<typename T>
__device__ void proj_body(const u16* xc, const u16* xcT, const T* xpw,
                          u16* dtsg, u32* BCg, float* xt){
  int blk = blockIdx.x;
  int tile = blk & 127; int s = (blk >> 7) & 1; int b = blk >> 8;
  int q0 = tile * 32;
  const u16* src = (s ? xcT : xc) + (long)b*Di*Ln;
  for (int i = threadIdx.x; i < Di*32; i += 256){
    int d = i >> 5, j = i & 31;
    xt[d*33 + j] = bfr(src[(long)d*Ln + q0 + j]);
  }
  __syncthreads();
  for (int o = threadIdx.x; o < 2*22*32; o += 256){
    int j = o & 31; int t = (o >> 5) % 22; int kk = o / (22*32);
    int k = s + 2*kk;
    int q = q0 + j;
    int l = kk ? (Ln-1-q) : q;
    long base = (long)(b*Kn + k)*Ln + l;
    if (t < 6){
      const T* wr = xpw + ((long)k*38 + t)*Di;
      float acc = 0.f;
      for (int d2 = 0; d2 < Di; d2 += 4){
        float4 w4 = ldv4(wr, d2);
        acc += w4.x*xt[d2*33+j] + w4.y*xt[(d2+1)*33+j]
             + w4.z*xt[(d2+2)*33+j] + w4.w*xt[(d2+3)*33+j];
      }
      dtsg[base*6 + t] = fbr(acc);
    } else {
      int n = t - 6;
      const T* wB = xpw + ((long)k*38 + 6 + n)*Di;
      const T* wC = xpw + ((long)k*38 + 22 + n)*Di;
      float aB = 0.f, aC = 0.f;
      for (int d2 = 0; d2 < Di; d2 += 4){
        float4 b4 = ldv4(wB, d2);
        float4 c4 = ldv4(wC, d2);
        float x0 = xt[d2*33+j], x1 = xt[(d2+1)*33+j], x2 = xt[(d2+2)*33+j], x3 = xt[(d2+3)*33+j];
        aB += b4.x*x0 + b4.y*x1 + b4.z*x2 + b4.w*x3;
        aC += c4.x*x0 + c4.y*x1 + c4.z*x2 + c4.w*x3;
      }
      BCg[base*16 + n] = (u32)fbr(aB) | ((u32)fbr(aC) << 16);
    }
  }
}
__global__ __launch_bounds__(256) void k_proj(const u16* xc, const u16* xcT, const void* xpw,
                                              u16* dtsg, u32* BCg, const int* flag){
  __shared__ float xt[Di*33];
  if (*flag) proj_body<float>(xc, xcT, (const float*)xpw, dtsg, BCg, xt);
  else       proj_body<bf16 >(xc, xcT, (const bf16* )xpw, dtsg, BCg, xt);
}

// -------------------------------------------------------------- zero y buffer
__global__ void k_zero(float4* p, long n4){
  long i = (long)blockIdx.x*blockDim.x + threadIdx.x;
  long st = (long)gridDim.x*blockDim.x;
  float4 z = make_float4(0.f,0.f,0.f,0.f);
  for (; i < n4; i += st) p[i] = z;
}

// ------------------------------------------- selective scan (1 wave = 4d x 16n)
template<typename T>
__device__ void scan_body(const u16* xc, const u16* xcT, const u16* dtsg, const u32* BCg,
                          const T* Alog, const T* dtw, const T* dtb, float* y,
                          float* sdts, float2* sdd, float2* sbc, float* sly, float* swt){
  int blk = blockIdx.x;
  int dgrp = blk % 48; int k = (blk/48) & 3; int b = blk/192;
  int d0 = dgrp * 4;
  int tid = threadIdx.x;
  int dl_ = tid >> 4, n = tid & 15;
  bool rev = k >= 2, odd = k & 1;
  const u16* src = (odd ? xcT : xc) + ((long)b*Di + d0)*Ln;
  const u16* dlg = dtsg + (long)(b*Kn + k)*Ln*6;
  const u32* bcg = BCg + (long)(b*Kn + k)*Ln*16;
  float* yb = y + (long)b*Ln*Di;
  if (tid < 24) swt[tid] = ldv(dtw, ((long)k*Di + d0 + tid/6)*6 + tid%6);
  else if (tid < 28) swt[tid] = ldv(dtb, k*Di + d0 + (tid-24));     // swt[24..27] = bias
  float a = -__expf(ldv(Alog, (d0 + dl_)*16 + n));
  float h = 0.f;
  __syncthreads();
  for (int t = 0; t < 32; ++t){
    int l0 = t * 128;
    for (int i = tid; i < 768; i += 64)
      sdts[(i % 6)*132 + i/6] = bfr(dlg[(long)l0*6 + i]);
    for (int i = tid; i < 2048; i += 64){
      u32 v = bcg[(long)l0*16 + i];
      sbc[i] = make_float2(bfr((u16)(v & 0xffff)), bfr((u16)(v >> 16)));
    }
    __syncthreads();
    for (int i = tid; i < 512; i += 64){
      int dd = i >> 7, j = i & 127;
      float xv = swt[24 + dd];
      #pragma unroll
      for (int r = 0; r < 6; ++r) xv += swt[dd*6 + r] * sdts[r*132 + j];
      float dlv = splus(xv);
      int l = l0 + j; int pos = rev ? (Ln-1-l) : l;
      float uv = bfr(src[(long)dd*Ln + pos]);
      sdd[dd*128 + j] = make_float2(dlv, dlv * uv);
    }
    __syncthreads();
    #pragma unroll 4
    for (int j = 0; j < 128; ++j){
      float2 dv = sdd[dl_*128 + j];
      float2 bc = sbc[j*16 + n];
      float ex = __expf(dv.x * a);
      h = ex*h + dv.y*bc.x;
      float yv = h * bc.y;
      yv += __shfl_xor(yv, 1);
      yv += __shfl_xor(yv, 2);
      yv += __shfl_xor(yv, 4);
      yv += __shfl_xor(yv, 8);
      if (n == 0) sly[dl_*129 + j] = yv;
    }
    __syncthreads();
    for (int i = tid; i < 512; i += 64){
      int dd = i & 3, j = i >> 2;
      int l = l0 + j; int le = rev ? (Ln-1-l) : l;
      int sp = odd ? ((le & 63)*64 + (le >> 6)) : le;
      atomicAdd(&yb[(long)sp*Di + d0 + dd], sly[dd*129 + j]);
    }
    __syncthreads();
  }
}
__global__ __launch_bounds__(64) void k_scan(const u16* xc, const u16* xcT, const u16* dtsg,
                                             const u32* BCg, const void* Alog, const void* dtw,
                                             const void* dtb, float* y, const int* flag){
  __shared__ float sdts[6*132];
  __shared__ float2 sdd[4*128];
  __shared__ float2 sbc[128*16];
  __shared__ float sly[4*129];
  __shared__ float swt[28];
  if (*flag) scan_body<float>(xc, xcT, dtsg, BCg, (const float*)Alog, (const float*)dtw,
                              (const float*)dtb, y, sdts, sdd, sbc, sly, swt);
  else       scan_body<bf16 >(xc, xcT, dtsg, BCg, (const bf16* )Alog, (const bf16* )dtw,
                              (const bf16* )dtb, y, sdts, sdd, sbc, sly, swt);
}

// -------------------- skip + LayerNorm + gate + out_proj (reads merged y)
template<typename T>
__device__ void out_body(const float* y, const u16* xc, const u16* Z, const T* Dsv,
                         const T* lnw, const T* lnb, const T* wo, T* out, long obase,
                         float* ty, float* sDs){
  int b = blockIdx.x >> 6, h = blockIdx.x & 63;
  int tid = threadIdx.x;
  const u16* xcb = xc + (long)b*Di*Ln;
  const float* yb = y + (long)b*Ln*Di;
  const u16* Zb = Z + (long)b*Ln*Di;
  if (tid < Di)
    sDs[tid] = ldv(Dsv, tid) + ldv(Dsv, Di+tid) + ldv(Dsv, 2*Di+tid) + ldv(Dsv, 3*Di+tid);
  __syncthreads();
  for (int i = tid; i < Di*64; i += 256){
    int d = i >> 6, j = i & 63;
    ty[d*65 + j] = sDs[d] * bfr(xcb[(long)d*Ln + h*64 + j]);
  }
  __syncthreads();
  for (int i = tid; i < Di*64; i += 256){
    int j = i / 192, d = i % 192;     // coalesced y reads
    ty[d*65 + j] += yb[(long)(h*64 + j)*Di + d];
  }
  __syncthreads();
  int jj = tid >> 2, part = tid & 3;
  float s = 0.f, s2 = 0.f;
  for (int c = part*48; c < part*48 + 48; ++c){
    float v = ty[c*65 + jj]; s += v; s2 += v*v;
  }
  s += __shfl_xor(s, 1); s2 += __shfl_xor(s2, 1);
  s += __shfl_xor(s, 2); s2 += __shfl_xor(s2, 2);
  float mu = s * (1.f/192.f);
  float var = s2 * (1.f/192.f) - mu*mu;
  float rstd = rsqrtf(fmaxf(var, 0.f) + 1e-5f);
  long zbase = ((long)h*64 + jj)*Di;
  for (int c = part*48; c < part*48 + 48; ++c){
    float zv = bfr(Zb[zbase + c]);
    float g = zv / (1.f + __expf(-zv));
    float yn = (ty[c*65 + jj] - mu) * rstd * ldv(lnw, c) + ldv(lnb, c);
    ty[c*65 + jj] = yn * g;
  }
  __syncthreads();
  long ob = obase + ((long)b*Ln + h*64 + jj)*Cm;
  for (int o = part; o < Cm; o += 4){
    const T* wr = wo + (long)o*Di;
    float acc = 0.f;
    for (int c = 0; c < Di; c += 4){
      float4 w4 = ldv4(wr, c);
      acc += w4.x*ty[c*65+jj] + w4.y*ty[(c+1)*65+jj]
           + w4.z*ty[(c+2)*65+jj] + w4.w*ty[(c+3)*65+jj];
    }
    stv(out, ob + o, acc);
  }
}
__global__ __launch_bounds__(256) void k_out(const float* y, const u16* xc, const u16* Z,
                                             const void* Dsv, const void* lnw, const void* lnb,
                                             const void* wo, void* out, long obase, const int* flag){
  __shared__ float ty[Di*65];
  __shared__ float sDs[Di];
  if (*flag) out_body<float>(y, xc, Z, (const float*)Dsv, (const float*)lnw, (const float*)lnb,
                             (const float*)wo, (float*)out, obase, ty, sDs);
  else       out_body<bf16 >(y, xc, Z, (const bf16* )Dsv, (const bf16* )lnw, (const bf16* )lnb,
                             (const bf16* )wo, (bf16* )out, obase, ty, sDs);
}

extern "C" void kernel_launch(void* const* d_in, const int* in_sizes, int n_in,
                              void* d_out, int out_size, void* d_ws, size_t ws_size,
                              hipStream_t stream){
  const void* x    = d_in[0];
  const void* ipw  = d_in[1];
  const void* cw   = d_in[2];
  const void* cb   = d_in[3];
  const void* xpw  = d_in[4];
  const void* dtw  = d_in[5];
  const void* dtb  = d_in[6];
  const void* Alog = d_in[7];
  const void* Dsv  = d_in[8];
  const void* lnw  = d_in[9];
  const void* lnb  = d_in[10];
  const void* wo   = d_in[11];

  // per-batch footprint: 4 bf16 planes + dts + BC + f32 y = 10.19 MB
  const size_t PLANE = (size_t)Ln*Di*2;          // 1.57 MB
  const size_t DTS   = (size_t)Kn*Ln*6*2;        // 0.19 MB
  const size_t BCB   = (size_t)Kn*Ln*16*4;       // 1.05 MB
  const size_t YB    = (size_t)Ln*Di*4;          // 3.15 MB
  const size_t perB  = 4*PLANE + DTS + BCB + YB;
  int Bc = 1;
  for (int c : {8, 4, 2, 1}) if (256 + (size_t)c*perB <= ws_size){ Bc = c; break; }
  int nch = 8 / Bc;

  char* base = (char*)d_ws;
  int*  flag = (int*)base;
  u16* Z   = (u16*)(base + 256);
  u16* xc  = Z   + (size_t)Bc*Ln*Di;
  u16* xcT = xc  + (size_t)Bc*Ln*Di;
  u16* Xb  = xcT + (size_t)Bc*Ln*Di;
  u16* dts = Xb  + (size_t)Bc*Ln*Di;
  u32* BC  = (u32*)(dts + (size_t)Bc*Kn*Ln*6);
  float* y = (float*)(BC + (size_t)Bc*Kn*Ln*16);

  k_detect<<<1, 256, 0, stream>>>((const u16*)x, flag);

  for (int ch = 0; ch < nch; ++ch){
    long xoff = (long)ch*Bc*Ln*Cm;
    k_inproj   <<<Bc*Ln/8,   384, 0, stream>>>(x, xoff, ipw, Xb, Z, flag);
    k_conv     <<<Bc*Hn,     256, 0, stream>>>(Xb, cw, cb, xc, flag);
    k_transpose<<<Bc*Di,     256, 0, stream>>>(xc, xcT);
    k_proj     <<<Bc*256,    256, 0, stream>>>(xc, xcT, xpw, dts, BC, flag);
    k_zero     <<<512,       256, 0, stream>>>((float4*)y, (long)Bc*Ln*Di/4);
    k_scan     <<<Bc*192,     64, 0, stream>>>(xc, xcT, dts, BC, Alog, dtw, dtb, y, flag);
    k_out      <<<Bc*Hn,     256, 0, stream>>>(y, xc, Z, Dsv, lnw, lnb, wo, d_out, xoff, flag);
  }
}

// Round 5
// 1755.464 us; speedup vs baseline: 6.0679x; 1.0191x over previous
//
#include <hip/hip_runtime.h>
#include <hip/hip_bf16.h>

typedef __hip_bfloat16 bf16;
typedef unsigned short u16;
typedef unsigned int   u32;

constexpr int Hn=64, Wn=64, Cm=96, Ln=4096, Di=192, Kn=4, Ns=16, Rr=6;
constexpr int Gc=16, CH=256;   // 16 chunks of 256 positions

static __device__ __forceinline__ float ldv(const float* p, long i){ return p[i]; }
static __device__ __forceinline__ float ldv(const bf16*  p, long i){ return __bfloat162float(p[i]); }
static __device__ __forceinline__ void  stv(float* p, long i, float v){ p[i] = v; }
static __device__ __forceinline__ void  stv(bf16*  p, long i, float v){ p[i] = __float2bfloat16(v); }
static __device__ __forceinline__ float bfr(u16 u){ return __uint_as_float((u32)u << 16); }
static __device__ __forceinline__ u16   fbr(float f){ bf16 h = __float2bfloat16(f); return *(u16*)&h; }
static __device__ __forceinline__ float4 ldv4(const float* p, long i){ return *(const float4*)(p + i); }
static __device__ __forceinline__ float4 ldv4(const bf16* p, long i){
  ushort4 u = *(const ushort4*)(p + i);
  return make_float4(bfr(u.x), bfr(u.y), bfr(u.z), bfr(u.w));
}
static __device__ __forceinline__ float splus(float x){ return (x > 15.f) ? x : log1pf(__expf(x)); }

// ------------------------------------------------ dtype detector (f32 vs bf16)
__global__ void k_detect(const u16* x, int* flag){
  __shared__ int cnt;
  if (threadIdx.x == 0) cnt = 0;
  __syncthreads();
  int local = 0;
  for (int i = threadIdx.x; i < 8192; i += 256){
    int e = (x[i] >> 7) & 0xFF;
    if (e != 0 && (e < 90 || e > 164)) local++;
  }
  atomicAdd(&cnt, local);
  __syncthreads();
  if (threadIdx.x == 0) *flag = (cnt > 400) ? 1 : 0;   // 1 => float32 inputs
}

// ---------------------------------------------------------------- in_proj GEMM
template<typename T>
__device__ void inproj_body(const T* x, const T* w, u16* Xb, u16* Z){
  __shared__ float xs[8*96];
  int c = threadIdx.x;
  long p0 = (long)blockIdx.x * 8;
  for (int i = c; i < 768; i += 384) xs[i] = ldv(x, p0*96 + i);
  __syncthreads();
  float acc[8] = {0,0,0,0,0,0,0,0};
  for (int kk = 0; kk < 96; kk += 4){
    float4 wv = ldv4(w, (long)c*96 + kk);
    #pragma unroll
    for (int p = 0; p < 8; ++p)
      acc[p] += wv.x*xs[p*96+kk] + wv.y*xs[p*96+kk+1]
              + wv.z*xs[p*96+kk+2] + wv.w*xs[p*96+kk+3];
  }
  if (c < Di){
    #pragma unroll
    for (int p = 0; p < 8; ++p) Xb[(p0+p)*Di + c] = fbr(acc[p]);
  } else {
    int c2 = c - Di;
    #pragma unroll
    for (int p = 0; p < 8; ++p) Z[(p0+p)*Di + c2] = fbr(acc[p]);
  }
}
__global__ __launch_bounds__(384) void k_inproj(const void* x, long xoff, const void* w,
                                                u16* Xb, u16* Z, const int* flag){
  if (*flag) inproj_body<float>((const float*)x + xoff, (const float*)w, Xb, Z);
  else       inproj_body<bf16 >((const bf16* )x + xoff, (const bf16* )w, Xb, Z);
}

// ---------------------------------------------------- depthwise conv3x3 + SiLU
template<typename T>
__device__ void conv_body(const u16* Xb, const T* cw, const T* cb, u16* xc, float* wle, u16* tl){
  float* ble = wle + Di*9;
  int b = blockIdx.x >> 6, h = blockIdx.x & 63;
  for (int i = threadIdx.x; i < Di*9; i += 256) wle[i] = ldv(cw, i);
  for (int i = threadIdx.x; i < Di;   i += 256) ble[i] = ldv(cb, i);
  __syncthreads();
  const u16* Xbb = Xb + (long)b*Ln*Di;
  u16* xcb = xc + (long)b*Di*Ln;
  for (int i = threadIdx.x; i < Di*Wn; i += 256){
    int w = i / 192, d = i % 192;
    float acc = ble[d];
    #pragma unroll
    for (int dh = -1; dh <= 1; ++dh){
      int hh = h + dh; if (hh < 0 || hh > 63) continue;
      #pragma unroll
      for (int dw = -1; dw <= 1; ++dw){
        int ww = w + dw; if (ww < 0 || ww > 63) continue;
        acc += wle[d*9 + (dh+1)*3 + (dw+1)] * bfr(Xbb[(long)(hh*64+ww)*Di + d]);
      }
    }
    float sv = acc / (1.f + __expf(-acc));
    tl[d*66 + w] = fbr(sv);
  }
  __syncthreads();
  for (int i = threadIdx.x; i < Di*Wn; i += 256){
    int d = i >> 6, w = i & 63;
    xcb[(long)d*Ln + h*64 + w] = tl[d*66 + w];
  }
}
__global__ __launch_bounds__(256) void k_conv(const u16* Xb, const void* cw, const void* cb,
                                              u16* xc, const int* flag){
  __shared__ float wle[Di*9 + Di];
  __shared__ u16 tl[Di*66];
  if (*flag) conv_body<float>(Xb, (const float*)cw, (const float*)cb, xc, wle, tl);
  else       conv_body<bf16 >(Xb, (const bf16* )cw, (const bf16* )cb, xc, wle, tl);
}

// ------------------------------------------------------- 64x64 tile transpose
__global__ __launch_bounds__(256) void k_transpose(const u16* xc, u16* xcT){
  long bd = blockIdx.x;
  const u16* src = xc + bd*Ln;
  u16* dst = xcT + bd*Ln;
  __shared__ u16 tl[64*65];
  for (int i = threadIdx.x; i < 4096; i += 256) tl[(i>>6)*65 + (i&63)] = src[i];
  __syncthreads();
  for (int i = threadIdx.x; i < 4096; i += 256){
    int wq = i >> 6, hq = i & 63;
    dst[i] = tl[hq*65 + wq];
  }
}

// --------------------------------------------- x_proj (dts + packed B/C, scan order)
template<typename T>
__device__ void proj_body(const u16* xc, const u16* xcT, const T* xpw,
                          u16* dtsg, u32* BCg, float* xt){
  int blk = blockIdx.x;
  int tile = blk & 127; int s = (blk >> 7) & 1; int b = blk >> 8;
  int q0 = tile * 32;
  const u16* src = (s ? xcT : xc) + (long)b*Di*Ln;
  for (int i = threadIdx.x; i < Di*32; i += 256){
    int d = i >> 5, j = i & 31;
    xt[d*33 + j] = bfr(src[(long)d*Ln + q0 + j]);
  }
  __syncthreads();
  for (int o = threadIdx.x; o < 2*22*32; o += 256){
    int j = o & 31; int t = (o >> 5) % 22; int kk = o / (22*32);
    int k = s + 2*kk;
    int q = q0 + j;
    int l = kk ? (Ln-1-q) : q;
    long base = (long)(b*Kn + k)*Ln + l;
    if (t < 6){
      const T* wr = xpw + ((long)k*38 + t)*Di;
      float acc = 0.f;
      for (int d2 = 0; d2 < Di; d2 += 4){
        float4 w4 = ldv4(wr, d2);
        acc += w4.x*xt[d2*33+j] + w4.y*xt[(d2+1)*33+j]
             + w4.z*xt[(d2+2)*33+j] + w4.w*xt[(d2+3)*33+j];
      }
      dtsg[base*6 + t] = fbr(acc);
    } else {
      int n = t - 6;
      const T* wB = xpw + ((long)k*38 + 6 + n)*Di;
      const T* wC = xpw + ((long)k*38 + 22 + n)*Di;
      float aB = 0.f, aC = 0.f;
      for (int d2 = 0; d2 < Di; d2 += 4){
        float4 b4 = ldv4(wB, d2);
        float4 c4 = ldv4(wC, d2);
        float x0 = xt[d2*33+j], x1 = xt[(d2+1)*33+j], x2 = xt[(d2+2)*33+j], x3 = xt[(d2+3)*33+j];
        aB += b4.x*x0 + b4.y*x1 + b4.z*x2 + b4.w*x3;
        aC += c4.x*x0 + c4.y*x1 + c4.z*x2 + c4.w*x3;
      }
      BCg[base*16 + n] = (u32)fbr(aB) | ((u32)fbr(aC) << 16);
    }
  }
}
__global__ __launch_bounds__(256) void k_proj(const u16* xc, const u16* xcT, const void* xpw,
                                              u16* dtsg, u32* BCg, const int* flag){
  __shared__ float xt[Di*33];
  if (*flag) proj_body<float>(xc, xcT, (const float*)xpw, dtsg, BCg, xt);
  else       proj_body<bf16 >(xc, xcT, (const bf16* )xpw, dtsg, BCg, xt);
}

// ---------------------------------------------------------------- scan helpers
// block decode for scan1/scan2: blk -> (b,k,dgrp,g); 1 wave = 4d x 16n
struct ScanCtx {
  int b, k, dgrp, g, d0, dl_, n;
  bool rev, odd;
  long pqIdx;
};
static __device__ __forceinline__ ScanCtx scan_ctx(int blk, int tid){
  ScanCtx c;
  c.g = blk % Gc; c.dgrp = (blk/Gc) % 48; c.k = (blk/(Gc*48)) & 3; c.b = blk/(Gc*192);
  c.d0 = c.dgrp*4; c.dl_ = tid >> 4; c.n = tid & 15;
  c.rev = c.k >= 2; c.odd = c.k & 1;
  c.pqIdx = ((((long)(c.b*Kn + c.k)*48 + c.dgrp)*Gc + c.g)*64) + tid;
  return c;
}

// stage one 128-tile: sdts (transposed dts), then sdd = (delta, delta*u)
template<typename T>
static __device__ __forceinline__ void stage_tile(int tid, int l0, bool rev,
    const u16* src, const u16* dlg, const u32* bcg,
    float* sdts, float2* sdd, u32* sbc, const float* swt){
  for (int i = tid; i < 768; i += 64)
    sdts[(i % 6)*132 + i/6] = bfr(dlg[(long)l0*6 + i]);
  for (int i = tid; i < 2048; i += 64)
    sbc[i] = bcg[(long)l0*16 + i];
  __syncthreads();
  for (int i = tid; i < 512; i += 64){
    int dd = i >> 7, j = i & 127;
    float xv = swt[24 + dd];
    #pragma unroll
    for (int r = 0; r < 6; ++r) xv += swt[dd*6 + r] * sdts[r*132 + j];
    float dlv = splus(xv);
    int l = l0 + j; int pos = rev ? (Ln-1-l) : l;
    float uv = bfr(src[(long)dd*Ln + pos]);
    sdd[dd*132 + j] = make_float2(dlv, dlv * uv);
  }
  __syncthreads();
}

// ---------------------- scan pass 1: per-chunk transfer (P = exp(a*S), Q = h)
template<typename T>
__device__ void scan1_body(const u16* xc, const u16* xcT, const u16* dtsg, const u32* BCg,
                           const T* Alog, const T* dtw, const T* dtb, float2* PQ,
                           float* sdts, float2* sdd, u32* sbc, float* swt){
  int tid = threadIdx.x;
  ScanCtx c = scan_ctx(blockIdx.x, tid);
  const u16* src = (c.odd ? xcT : xc) + ((long)c.b*Di + c.d0)*Ln;
  const u16* dlg = dtsg + (long)(c.b*Kn + c.k)*Ln*6;
  const u32* bcg = BCg + (long)(c.b*Kn + c.k)*Ln*16;
  if (tid < 24) swt[tid] = ldv(dtw, ((long)c.k*Di + c.d0 + tid/6)*6 + tid%6);
  else if (tid < 28) swt[tid] = ldv(dtb, c.k*Di + c.d0 + (tid-24));
  float a = -__expf(ldv(Alog, (c.d0 + c.dl_)*16 + c.n));
  float h = 0.f, S = 0.f;
  __syncthreads();
  for (int t = 0; t < CH/128; ++t){
    int l0 = c.g*CH + t*128;
    stage_tile<T>(tid, l0, c.rev, src, dlg, bcg, sdts, sdd, sbc, swt);
    #pragma unroll 4
    for (int j = 0; j < 128; ++j){
      float2 dv = sdd[c.dl_*132 + j];
      float bb = bfr((u16)(sbc[j*16 + c.n] & 0xffff));
      h = __expf(dv.x * a)*h + dv.y*bb;
      S += dv.x;
    }
    __syncthreads();
  }
  PQ[c.pqIdx] = make_float2(__expf(a*S), h);
}
__global__ __launch_bounds__(64) void k_scan1(const u16* xc, const u16* xcT, const u16* dtsg,
                                              const u32* BCg, const void* Alog, const void* dtw,
                                              const void* dtb, float2* PQ, const int* flag){
  __shared__ float sdts[6*132];
  __shared__ float2 sdd[4*132];
  __shared__ u32 sbc[2048];
  __shared__ float swt[28];
  if (*flag) scan1_body<float>(xc, xcT, dtsg, BCg, (const float*)Alog, (const float*)dtw,
                               (const float*)dtb, PQ, sdts, sdd, sbc, swt);
  else       scan1_body<bf16 >(xc, xcT, dtsg, BCg, (const bf16* )Alog, (const bf16* )dtw,
                               (const bf16* )dtb, PQ, sdts, sdd, sbc, swt);
}

// ---------------------- cross-chunk fixup: Hin[g] = scan of (P,Q) over g
__global__ __launch_bounds__(64) void k_fix(const float2* PQ, float* Hin){
  int blk = blockIdx.x;
  long base = ((long)(blk/192*Kn + (blk/48)%4)*48 + blk%48)*Gc;
  float h = 0.f;
  for (int g = 0; g < Gc; ++g){
    long idx = (base + g)*64 + threadIdx.x;
    Hin[idx] = h;
    float2 pq = PQ[idx];
    h = pq.x*h + pq.y;
  }
}

// ---------------------- scan pass 2: rescan from Hin, emit ys planes
template<typename T>
__device__ void scan2_body(const u16* xc, const u16* xcT, const u16* dtsg, const u32* BCg,
                           const T* Alog, const T* dtw, const T* dtb, const float* Hin,
                           u16* ys, float* sdts, float2* sdd, u32* sbc, float* sly, float* swt){
  int tid = threadIdx.x;
  ScanCtx c = scan_ctx(blockIdx.x, tid);
  const u16* src = (c.odd ? xcT : xc) + ((long)c.b*Di + c.d0)*Ln;
  const u16* dlg = dtsg + (long)(c.b*Kn + c.k)*Ln*6;
  const u32* bcg = BCg + (long)(c.b*Kn + c.k)*Ln*16;
  u16* yb = ys + (long)(c.b*Kn + c.k)*Ln*Di;
  if (tid < 24) swt[tid] = ldv(dtw, ((long)c.k*Di + c.d0 + tid/6)*6 + tid%6);
  else if (tid < 28) swt[tid] = ldv(dtb, c.k*Di + c.d0 + (tid-24));
  float a = -__expf(ldv(Alog, (c.d0 + c.dl_)*16 + c.n));
  float h = Hin[c.pqIdx];
  __syncthreads();
  for (int t = 0; t < CH/128; ++t){
    int l0 = c.g*CH + t*128;
    stage_tile<T>(tid, l0, c.rev, src, dlg, bcg, sdts, sdd, sbc, swt);
    #pragma unroll 4
    for (int j = 0; j < 128; ++j){
      float2 dv = sdd[c.dl_*132 + j];
      u32 bc = sbc[j*16 + c.n];
      h = __expf(dv.x * a)*h + dv.y*bfr((u16)(bc & 0xffff));
      float yv = h * bfr((u16)(bc >> 16));
      yv += __shfl_xor(yv, 1);
      yv += __shfl_xor(yv, 2);
      yv += __shfl_xor(yv, 4);
      yv += __shfl_xor(yv, 8);
      if (c.n == 0) sly[c.dl_*130 + j] = yv;
    }
    __syncthreads();
    for (int i = tid; i < 512; i += 64){
      int dd = i & 3, j = i >> 2;
      int l = l0 + j; int le = c.rev ? (Ln-1-l) : l;
      int sp = c.odd ? ((le & 63)*64 + (le >> 6)) : le;
      yb[(long)sp*Di + c.d0 + dd] = fbr(sly[dd*130 + j]);
    }
    __syncthreads();
  }
}
__global__ __launch_bounds__(64) void k_scan2(const u16* xc, const u16* xcT, const u16* dtsg,
                                              const u32* BCg, const void* Alog, const void* dtw,
                                              const void* dtb, const float* Hin, u16* ys,
                                              const int* flag){
  __shared__ float sdts[6*132];
  __shared__ float2 sdd[4*132];
  __shared__ u32 sbc[2048];
  __shared__ float sly[4*130];
  __shared__ float swt[28];
  if (*flag) scan2_body<float>(xc, xcT, dtsg, BCg, (const float*)Alog, (const float*)dtw,
                               (const float*)dtb, Hin, ys, sdts, sdd, sbc, sly, swt);
  else       scan2_body<bf16 >(xc, xcT, dtsg, BCg, (const bf16* )Alog, (const bf16* )dtw,
                               (const bf16* )dtb, Hin, ys, sdts, sdd, sbc, sly, swt);
}

// -------------------- merge + skip + LayerNorm + gate + out_proj
template<typename T>
__device__ void out_body(const u16* ys, const u16* xc, const u16* Z, const T* Dsv,
                         const T* lnw, const T* lnb, const T* wo, T* out, long obase,
                         float* ty, float* sDs){
  int b = blockIdx.x >> 6, h = blockIdx.x & 63;
  int tid = threadIdx.x;
  const u16* xcb = xc + (long)b*Di*Ln;
  const u16* Zb = Z + (long)b*Ln*Di;
  const u16* pl0 = ys + (long)(b*Kn + 0)*Ln*Di;
  const u16* pl1 = ys + (long)(b*Kn + 1)*Ln*Di;
  const u16* pl2 = ys + (long)(b*Kn + 2)*Ln*Di;
  const u16* pl3 = ys + (long)(b*Kn + 3)*Ln*Di;
  if (tid < Di)
    sDs[tid] = ldv(Dsv, tid) + ldv(Dsv, Di+tid) + ldv(Dsv, 2*Di+tid) + ldv(Dsv, 3*Di+tid);
  __syncthreads();
  for (int i = tid; i < Di*64; i += 256){
    int j = i / 192, d = i % 192;
    long ls = (long)(h*64 + j)*Di + d;
    long lt = (long)(j*64 + h)*Di + d;
    ty[d*65 + j] = bfr(pl0[ls]) + bfr(pl2[ls]) + bfr(pl1[lt]) + bfr(pl3[lt]);
  }
  __syncthreads();
  for (int i = tid; i < Di*64; i += 256){
    int d = i >> 6, j = i & 63;
    ty[d*65 + j] += sDs[d] * bfr(xcb[(long)d*Ln + h*64 + j]);
  }
  __syncthreads();
  int jj = tid >> 2, part = tid & 3;
  float s = 0.f, s2 = 0.f;
  for (int cix = part*48; cix < part*48 + 48; ++cix){
    float v = ty[cix*65 + jj]; s += v; s2 += v*v;
  }
  s += __shfl_xor(s, 1); s2 += __shfl_xor(s2, 1);
  s += __shfl_xor(s, 2); s2 += __shfl_xor(s2, 2);
  float mu = s * (1.f/192.f);
  float var = s2 * (1.f/192.f) - mu*mu;
  float rstd = rsqrtf(fmaxf(var, 0.f) + 1e-5f);
  long zbase = ((long)h*64 + jj)*Di;
  for (int cix = part*48; cix < part*48 + 48; ++cix){
    float zv = bfr(Zb[zbase + cix]);
    float g = zv / (1.f + __expf(-zv));
    float yn = (ty[cix*65 + jj] - mu) * rstd * ldv(lnw, cix) + ldv(lnb, cix);
    ty[cix*65 + jj] = yn * g;
  }
  __syncthreads();
  long ob = obase + ((long)b*Ln + h*64 + jj)*Cm;
  for (int o = part; o < Cm; o += 4){
    const T* wr = wo + (long)o*Di;
    float acc = 0.f;
    for (int cix = 0; cix < Di; cix += 4){
      float4 w4 = ldv4(wr, cix);
      acc += w4.x*ty[cix*65+jj] + w4.y*ty[(cix+1)*65+jj]
           + w4.z*ty[(cix+2)*65+jj] + w4.w*ty[(cix+3)*65+jj];
    }
    stv(out, ob + o, acc);
  }
}
__global__ __launch_bounds__(256) void k_out(const u16* ys, const u16* xc, const u16* Z,
                                             const void* Dsv, const void* lnw, const void* lnb,
                                             const void* wo, void* out, long obase, const int* flag){
  __shared__ float ty[Di*65];
  __shared__ float sDs[Di];
  if (*flag) out_body<float>(ys, xc, Z, (const float*)Dsv, (const float*)lnw, (const float*)lnb,
                             (const float*)wo, (float*)out, obase, ty, sDs);
  else       out_body<bf16 >(ys, xc, Z, (const bf16* )Dsv, (const bf16* )lnw, (const bf16* )lnb,
                             (const bf16* )wo, (bf16* )out, obase, ty, sDs);
}

extern "C" void kernel_launch(void* const* d_in, const int* in_sizes, int n_in,
                              void* d_out, int out_size, void* d_ws, size_t ws_size,
                              hipStream_t stream){
  const void* x    = d_in[0];
  const void* ipw  = d_in[1];
  const void* cw   = d_in[2];
  const void* cb   = d_in[3];
  const void* xpw  = d_in[4];
  const void* dtw  = d_in[5];
  const void* dtb  = d_in[6];
  const void* Alog = d_in[7];
  const void* Dsv  = d_in[8];
  const void* lnw  = d_in[9];
  const void* lnb  = d_in[10];
  const void* wo   = d_in[11];

  // per-batch bytes: 4 bf16 planes + dts + BC + ys(bf16) + PQ + Hin
  const size_t PLANE = (size_t)Ln*Di*2;             // 1.57 MB
  const size_t DTS   = (size_t)Kn*Ln*6*2;           // 0.19 MB
  const size_t BCB   = (size_t)Kn*Ln*16*4;          // 1.05 MB
  const size_t YSB   = (size_t)Kn*Ln*Di*2;          // 6.29 MB
  const size_t PQB   = (size_t)Kn*48*Gc*64*8;       // 1.57 MB
  const size_t HIB   = PQB/2;                       // 0.79 MB
  const size_t perB  = 4*PLANE + DTS + BCB + YSB + PQB + HIB;   // ~16.2 MB
  int Bc = 1;
  for (int c : {8, 4, 2, 1}) if (256 + (size_t)c*perB <= ws_size){ Bc = c; break; }
  int nch = 8 / Bc;

  char* base = (char*)d_ws;
  int*  flag = (int*)base;
  u16* Z    = (u16*)(base + 256);
  u16* xc   = Z   + (size_t)Bc*Ln*Di;
  u16* xcT  = xc  + (size_t)Bc*Ln*Di;
  u16* Xb   = xcT + (size_t)Bc*Ln*Di;
  u16* dts  = Xb  + (size_t)Bc*Ln*Di;
  u32* BC   = (u32*)(dts + (size_t)Bc*Kn*Ln*6);
  u16* ys   = (u16*)(BC + (size_t)Bc*Kn*Ln*16);
  float2* PQ = (float2*)(ys + (size_t)Bc*Kn*Ln*Di);
  float* Hin = (float*)(PQ + (size_t)Bc*Kn*48*Gc*64);

  k_detect<<<1, 256, 0, stream>>>((const u16*)x, flag);

  for (int ch = 0; ch < nch; ++ch){
    long xoff = (long)ch*Bc*Ln*Cm;
    k_inproj   <<<Bc*Ln/8,      384, 0, stream>>>(x, xoff, ipw, Xb, Z, flag);
    k_conv     <<<Bc*Hn,        256, 0, stream>>>(Xb, cw, cb, xc, flag);
    k_transpose<<<Bc*Di,        256, 0, stream>>>(xc, xcT);
    k_proj     <<<Bc*256,       256, 0, stream>>>(xc, xcT, xpw, dts, BC, flag);
    k_scan1    <<<Bc*Kn*48*Gc,   64, 0, stream>>>(xc, xcT, dts, BC, Alog, dtw, dtb, PQ, flag);
    k_fix      <<<Bc*192,        64, 0, stream>>>(PQ, Hin);
    k_scan2    <<<Bc*Kn*48*Gc,   64, 0, stream>>>(xc, xcT, dts, BC, Alog, dtw, dtb, Hin, ys, flag);
    k_out      <<<Bc*Hn,        256, 0, stream>>>(ys, xc, Z, Dsv, lnw, lnb, wo, d_out, xoff, flag);
  }
}

// Round 6
// 1200.237 us; speedup vs baseline: 8.8749x; 1.4626x over previous
//
#include <hip/hip_runtime.h>
#include <hip/hip_bf16.h>

typedef __hip_bfloat16 bf16;
typedef unsigned short u16;
typedef unsigned int   u32;

constexpr int Hn=64, Wn=64, Cm=96, Ln=4096, Di=192, Kn=4, Ns=16, Rr=6;
constexpr int Gc=32, CH=128;   // 32 chunks of 128 positions

static __device__ __forceinline__ float ldv(const float* p, long i){ return p[i]; }
static __device__ __forceinline__ float ldv(const bf16*  p, long i){ return __bfloat162float(p[i]); }
static __device__ __forceinline__ void  stv(float* p, long i, float v){ p[i] = v; }
static __device__ __forceinline__ void  stv(bf16*  p, long i, float v){ p[i] = __float2bfloat16(v); }
static __device__ __forceinline__ float bfr(u16 u){ return __uint_as_float((u32)u << 16); }
static __device__ __forceinline__ u16   fbr(float f){ bf16 h = __float2bfloat16(f); return *(u16*)&h; }
static __device__ __forceinline__ float4 ldv4(const float* p, long i){ return *(const float4*)(p + i); }
static __device__ __forceinline__ float4 ldv4(const bf16* p, long i){
  ushort4 u = *(const ushort4*)(p + i);
  return make_float4(bfr(u.x), bfr(u.y), bfr(u.z), bfr(u.w));
}
static __device__ __forceinline__ float splus(float x){ return (x > 15.f) ? x : log1pf(__expf(x)); }

// ------------------------------------------------ dtype detector (f32 vs bf16)
__global__ void k_detect(const u16* x, int* flag){
  __shared__ int cnt;
  if (threadIdx.x == 0) cnt = 0;
  __syncthreads();
  int local = 0;
  for (int i = threadIdx.x; i < 8192; i += 256){
    int e = (x[i] >> 7) & 0xFF;
    if (e != 0 && (e < 90 || e > 164)) local++;
  }
  atomicAdd(&cnt, local);
  __syncthreads();
  if (threadIdx.x == 0) *flag = (cnt > 400) ? 1 : 0;   // 1 => float32 inputs
}

// ---------------------------------------------------------------- in_proj GEMM
template<typename T>
__device__ void inproj_body(const T* x, const T* w, u16* Xb, u16* Z){
  __shared__ float xs[8*96];
  int c = threadIdx.x;
  long p0 = (long)blockIdx.x * 8;
  for (int i = c; i < 768; i += 384) xs[i] = ldv(x, p0*96 + i);
  __syncthreads();
  float acc[8] = {0,0,0,0,0,0,0,0};
  for (int kk = 0; kk < 96; kk += 4){
    float4 wv = ldv4(w, (long)c*96 + kk);
    #pragma unroll
    for (int p = 0; p < 8; ++p)
      acc[p] += wv.x*xs[p*96+kk] + wv.y*xs[p*96+kk+1]
              + wv.z*xs[p*96+kk+2] + wv.w*xs[p*96+kk+3];
  }
  if (c < Di){
    #pragma unroll
    for (int p = 0; p < 8; ++p) Xb[(p0+p)*Di + c] = fbr(acc[p]);
  } else {
    int c2 = c - Di;
    #pragma unroll
    for (int p = 0; p < 8; ++p) Z[(p0+p)*Di + c2] = fbr(acc[p]);
  }
}
__global__ __launch_bounds__(384) void k_inproj(const void* x, long xoff, const void* w,
                                                u16* Xb, u16* Z, const int* flag){
  if (*flag) inproj_body<float>((const float*)x + xoff, (const float*)w, Xb, Z);
  else       inproj_body<bf16 >((const bf16* )x + xoff, (const bf16* )w, Xb, Z);
}

// ------------------- depthwise conv3x3 + SiLU -> xcLD (L,D) and xcTLD (Lt,D)
template<typename T>
__device__ void conv_body(const u16* Xb, const T* cw, const T* cb,
                          u16* xcLD, u16* xcTLD, float* wle, u16* tl){
  float* ble = wle + Di*9;
  int b = blockIdx.x >> 6, h = blockIdx.x & 63;
  for (int i = threadIdx.x; i < Di*9; i += 256) wle[i] = ldv(cw, i);
  for (int i = threadIdx.x; i < Di;   i += 256) ble[i] = ldv(cb, i);
  __syncthreads();
  const u16* Xbb = Xb + (long)b*Ln*Di;
  u16* xa = xcLD  + (long)b*Ln*Di;
  u16* xb = xcTLD + (long)b*Ln*Di;
  for (int i = threadIdx.x; i < Di*Wn; i += 256){
    int w = i / 192, d = i % 192;
    float acc = ble[d];
    #pragma unroll
    for (int dh = -1; dh <= 1; ++dh){
      int hh = h + dh; if (hh < 0 || hh > 63) continue;
      #pragma unroll
      for (int dw = -1; dw <= 1; ++dw){
        int ww = w + dw; if (ww < 0 || ww > 63) continue;
        acc += wle[d*9 + (dh+1)*3 + (dw+1)] * bfr(Xbb[(long)(hh*64+ww)*Di + d]);
      }
    }
    float sv = acc / (1.f + __expf(-acc));
    tl[d*66 + w] = fbr(sv);
  }
  __syncthreads();
  for (int i = threadIdx.x; i < Di*Wn; i += 256){
    int w = i / 192, d = i % 192;
    u16 v = tl[d*66 + w];
    xa[(long)(h*64 + w)*Di + d] = v;
    xb[(long)(w*64 + h)*Di + d] = v;
  }
}
__global__ __launch_bounds__(256) void k_conv(const u16* Xb, const void* cw, const void* cb,
                                              u16* xcLD, u16* xcTLD, const int* flag){
  __shared__ float wle[Di*9 + Di];
  __shared__ u16 tl[Di*66];
  if (*flag) conv_body<float>(Xb, (const float*)cw, (const float*)cb, xcLD, xcTLD, wle, tl);
  else       conv_body<bf16 >(Xb, (const bf16* )cw, (const bf16* )cb, xcLD, xcTLD, wle, tl);
}

// --------------------------------------------- x_proj (dts + packed B/C, scan order)
template<typename T>
__device__ void proj_body(const u16* xcLD, const u16* xcTLD, const T* xpw,
                          u16* dtsg, u32* BCg, float* xt){
  int blk = blockIdx.x;
  int tile = blk & 127; int s = (blk >> 7) & 1; int b = blk >> 8;
  int q0 = tile * 32;
  const u16* src = (s ? xcTLD : xcLD) + (long)b*Ln*Di;
  for (int i = threadIdx.x; i < Di*32; i += 256){
    int j = i / 192, d = i % 192;
    xt[d*33 + j] = bfr(src[(long)(q0+j)*Di + d]);
  }
  __syncthreads();
  for (int o = threadIdx.x; o < 2*22*32; o += 256){
    int j = o & 31; int t = (o >> 5) % 22; int kk = o / (22*32);
    int k = s + 2*kk;
    int q = q0 + j;
    int l = kk ? (Ln-1-q) : q;
    long base = (long)(b*Kn + k)*Ln + l;
    if (t < 6){
      const T* wr = xpw + ((long)k*38 + t)*Di;
      float acc = 0.f;
      for (int d2 = 0; d2 < Di; d2 += 4){
        float4 w4 = ldv4(wr, d2);
        acc += w4.x*xt[d2*33+j] + w4.y*xt[(d2+1)*33+j]
             + w4.z*xt[(d2+2)*33+j] + w4.w*xt[(d2+3)*33+j];
      }
      dtsg[base*6 + t] = fbr(acc);
    } else {
      int n = t - 6;
      const T* wB = xpw + ((long)k*38 + 6 + n)*Di;
      const T* wC = xpw + ((long)k*38 + 22 + n)*Di;
      float aB = 0.f, aC = 0.f;
      for (int d2 = 0; d2 < Di; d2 += 4){
        float4 b4 = ldv4(wB, d2);
        float4 c4 = ldv4(wC, d2);
        float x0 = xt[d2*33+j], x1 = xt[(d2+1)*33+j], x2 = xt[(d2+2)*33+j], x3 = xt[(d2+3)*33+j];
        aB += b4.x*x0 + b4.y*x1 + b4.z*x2 + b4.w*x3;
        aC += c4.x*x0 + c4.y*x1 + c4.z*x2 + c4.w*x3;
      }
      BCg[base*16 + n] = (u32)fbr(aB) | ((u32)fbr(aC) << 16);
    }
  }
}
__global__ __launch_bounds__(256) void k_proj(const u16* xcLD, const u16* xcTLD, const void* xpw,
                                              u16* dtsg, u32* BCg, const int* flag){
  __shared__ float xt[Di*33];
  if (*flag) proj_body<float>(xcLD, xcTLD, (const float*)xpw, dtsg, BCg, xt);
  else       proj_body<bf16 >(xcLD, xcTLD, (const bf16* )xpw, dtsg, BCg, xt);
}

// -------------------------------- scan pass 1: lane=d, h[16]+a[16] in registers
template<typename T>
__device__ void scan1_body(const u16* xcLD, const u16* xcTLD, const u16* dtsg, const u32* BCg,
                           const T* Alog, const T* dtw, const T* dtb,
                           float* Sb, float* Qb, float* sdt, float* sB, u16* su){
  int tid = threadIdx.x, blk = blockIdx.x;
  int g = blk & (Gc-1); int k = (blk >> 5) & 3; int b = blk >> 7;
  bool rev = k >= 2, odd = k & 1;
  int d = tid;
  const u16* src = (odd ? xcTLD : xcLD) + (long)b*Ln*Di;
  const u16* dlg = dtsg + (long)(b*Kn + k)*Ln*6;
  const u32* bcg = BCg + (long)(b*Kn + k)*Ln*16;
  float w[6], a[16], h[16];
  #pragma unroll
  for (int r = 0; r < 6; ++r) w[r] = ldv(dtw, ((long)k*Di + d)*6 + r);
  float bias = ldv(dtb, k*Di + d);
  #pragma unroll
  for (int n = 0; n < 16; ++n){ a[n] = -__expf(ldv(Alog, (long)d*16 + n)); h[n] = 0.f; }
  float S = 0.f;
  for (int t = 0; t < CH/64; ++t){
    int l0 = g*CH + t*64;
    __syncthreads();
    for (int i = tid; i < 384; i += 192){ int j = i/6, c = i - 6*j; sdt[j*8 + c] = bfr(dlg[(long)l0*6 + i]); }
    for (int i = tid; i < 1024; i += 192){ u32 v = bcg[(long)l0*16 + i]; sB[i] = bfr((u16)(v & 0xffff)); }
    for (int i = tid; i < 64*192; i += 192){
      int j = i / 192, dd = i % 192;
      int l = l0 + j; int pos = rev ? (Ln-1-l) : l;
      su[i] = src[(long)pos*Di + dd];
    }
    __syncthreads();
    for (int j = 0; j < 64; ++j){
      float dl = bias;
      #pragma unroll
      for (int r = 0; r < 6; ++r) dl += w[r]*sdt[j*8 + r];
      dl = splus(dl);
      float du = dl * bfr(su[j*192 + d]);
      float Bv[16];
      *(float4*)&Bv[0]  = *(const float4*)&sB[j*16];
      *(float4*)&Bv[4]  = *(const float4*)&sB[j*16+4];
      *(float4*)&Bv[8]  = *(const float4*)&sB[j*16+8];
      *(float4*)&Bv[12] = *(const float4*)&sB[j*16+12];
      #pragma unroll
      for (int n = 0; n < 16; ++n) h[n] = __expf(dl*a[n])*h[n] + du*Bv[n];
      S += dl;
    }
  }
  long ci = (long)(b*Kn + k)*Gc + g;
  Sb[ci*Di + d] = S;
  #pragma unroll
  for (int n = 0; n < 16; ++n) Qb[ci*3072 + (long)d*16 + n] = h[n];
}
__global__ __launch_bounds__(192,3) void k_scan1(const u16* xcLD, const u16* xcTLD, const u16* dtsg,
                                                 const u32* BCg, const void* Alog, const void* dtw,
                                                 const void* dtb, float* Sb, float* Qb, const int* flag){
  __shared__ float sdt[64*8];
  __shared__ float sB[64*16];
  __shared__ u16 su[64*192];
  if (*flag) scan1_body<float>(xcLD, xcTLD, dtsg, BCg, (const float*)Alog, (const float*)dtw,
                               (const float*)dtb, Sb, Qb, sdt, sB, su);
  else       scan1_body<bf16 >(xcLD, xcTLD, dtsg, BCg, (const bf16* )Alog, (const bf16* )dtw,
                               (const bf16* )dtb, Sb, Qb, sdt, sB, su);
}

// ---------------------- cross-chunk fixup: Hin[g] = scan of (exp(a*S), Q) over g
template<typename T>
__device__ void fix_body(const float* Sb, const float* Qb, const T* Alog, float* Hin){
  int bk = blockIdx.x;
  for (int s = threadIdx.x; s < 3072; s += 256){
    int d = s >> 4, n = s & 15;
    float a = -__expf(ldv(Alog, (long)d*16 + n));
    float h = 0.f;
    for (int g = 0; g < Gc; ++g){
      long ci = (long)bk*Gc + g;
      Hin[ci*3072 + s] = h;
      h = __expf(a * Sb[ci*Di + d]) * h + Qb[ci*3072 + s];
    }
  }
}
__global__ __launch_bounds__(256) void k_fix(const float* Sb, const float* Qb, const void* Alog,
                                             float* Hin, const int* flag){
  if (*flag) fix_body<float>(Sb, Qb, (const float*)Alog, Hin);
  else       fix_body<bf16 >(Sb, Qb, (const bf16* )Alog, Hin);
}

// -------------------------------- scan pass 2: rescan from Hin, emit ys (L,D)
template<typename T>
__device__ void scan2_body(const u16* xcLD, const u16* xcTLD, const u16* dtsg, const u32* BCg,
                           const T* Alog, const T* dtw, const T* dtb, const float* Hin,
                           u16* ys, float* sdt, float* sB, float* sC, u16* su){
  int tid = threadIdx.x, blk = blockIdx.x;
  int g = blk & (Gc-1); int k = (blk >> 5) & 3; int b = blk >> 7;
  bool rev = k >= 2, odd = k & 1;
  int d = tid;
  const u16* src = (odd ? xcTLD : xcLD) + (long)b*Ln*Di;
  const u16* dlg = dtsg + (long)(b*Kn + k)*Ln*6;
  const u32* bcg = BCg + (long)(b*Kn + k)*Ln*16;
  u16* yb = ys + (long)(b*Kn + k)*Ln*Di;
  float w[6], a[16], h[16];
  #pragma unroll
  for (int r = 0; r < 6; ++r) w[r] = ldv(dtw, ((long)k*Di + d)*6 + r);
  float bias = ldv(dtb, k*Di + d);
  long ci = (long)(b*Kn + k)*Gc + g;
  #pragma unroll
  for (int n = 0; n < 16; ++n){
    a[n] = -__expf(ldv(Alog, (long)d*16 + n));
    h[n] = Hin[ci*3072 + (long)d*16 + n];
  }
  for (int t = 0; t < CH/64; ++t){
    int l0 = g*CH + t*64;
    __syncthreads();
    for (int i = tid; i < 384; i += 192){ int j = i/6, c = i - 6*j; sdt[j*8 + c] = bfr(dlg[(long)l0*6 + i]); }
    for (int i = tid; i < 1024; i += 192){
      u32 v = bcg[(long)l0*16 + i];
      sB[i] = bfr((u16)(v & 0xffff));
      sC[i] = bfr((u16)(v >> 16));
    }
    for (int i = tid; i < 64*192; i += 192){
      int j = i / 192, dd = i % 192;
      int l = l0 + j; int pos = rev ? (Ln-1-l) : l;
      su[i] = src[(long)pos*Di + dd];
    }
    __syncthreads();
    for (int j = 0; j < 64; ++j){
      float dl = bias;
      #pragma unroll
      for (int r = 0; r < 6; ++r) dl += w[r]*sdt[j*8 + r];
      dl = splus(dl);
      float du = dl * bfr(su[j*192 + d]);
      float Bv[16], Cv[16];
      *(float4*)&Bv[0]  = *(const float4*)&sB[j*16];
      *(float4*)&Bv[4]  = *(const float4*)&sB[j*16+4];
      *(float4*)&Bv[8]  = *(const float4*)&sB[j*16+8];
      *(float4*)&Bv[12] = *(const float4*)&sB[j*16+12];
      *(float4*)&Cv[0]  = *(const float4*)&sC[j*16];
      *(float4*)&Cv[4]  = *(const float4*)&sC[j*16+4];
      *(float4*)&Cv[8]  = *(const float4*)&sC[j*16+8];
      *(float4*)&Cv[12] = *(const float4*)&sC[j*16+12];
      float y = 0.f;
      #pragma unroll
      for (int n = 0; n < 16; ++n){
        h[n] = __expf(dl*a[n])*h[n] + du*Bv[n];
        y += h[n]*Cv[n];
      }
      int l = l0 + j; int le = rev ? (Ln-1-l) : l;
      int sp = odd ? ((le & 63)*64 + (le >> 6)) : le;
      yb[(long)sp*Di + d] = fbr(y);
    }
  }
}
__global__ __launch_bounds__(192,3) void k_scan2(const u16* xcLD, const u16* xcTLD, const u16* dtsg,
                                                 const u32* BCg, const void* Alog, const void* dtw,
                                                 const void* dtb, const float* Hin, u16* ys,
                                                 const int* flag){
  __shared__ float sdt[64*8];
  __shared__ float sB[64*16];
  __shared__ float sC[64*16];
  __shared__ u16 su[64*192];
  if (*flag) scan2_body<float>(xcLD, xcTLD, dtsg, BCg, (const float*)Alog, (const float*)dtw,
                               (const float*)dtb, Hin, ys, sdt, sB, sC, su);
  else       scan2_body<bf16 >(xcLD, xcTLD, dtsg, BCg, (const bf16* )Alog, (const bf16* )dtw,
                               (const bf16* )dtb, Hin, ys, sdt, sB, sC, su);
}

// -------------------- merge + skip + LayerNorm + gate + out_proj
template<typename T>
__device__ void out_body(const u16* ys, const u16* xcLD, const u16* Z, const T* Dsv,
                         const T* lnw, const T* lnb, const T* wo, T* out, long obase,
                         float* ty, float* sDs){
  int b = blockIdx.x >> 6, h = blockIdx.x & 63;
  int tid = threadIdx.x;
  const u16* xcb = xcLD + (long)b*Ln*Di;
  const u16* Zb = Z + (long)b*Ln*Di;
  const u16* pl0 = ys + (long)(b*Kn + 0)*Ln*Di;
  const u16* pl1 = ys + (long)(b*Kn + 1)*Ln*Di;
  const u16* pl2 = ys + (long)(b*Kn + 2)*Ln*Di;
  const u16* pl3 = ys + (long)(b*Kn + 3)*Ln*Di;
  if (tid < Di)
    sDs[tid] = ldv(Dsv, tid) + ldv(Dsv, Di+tid) + ldv(Dsv, 2*Di+tid) + ldv(Dsv, 3*Di+tid);
  __syncthreads();
  for (int i = tid; i < Di*64; i += 256){
    int j = i / 192, d = i % 192;
    long ls = (long)(h*64 + j)*Di + d;
    long lt = (long)(j*64 + h)*Di + d;
    ty[d*65 + j] = bfr(pl0[ls]) + bfr(pl2[ls]) + bfr(pl1[lt]) + bfr(pl3[lt])
                 + sDs[d]*bfr(xcb[ls]);
  }
  __syncthreads();
  int jj = tid >> 2, part = tid & 3;
  float s = 0.f, s2 = 0.f;
  for (int cix = part*48; cix < part*48 + 48; ++cix){
    float v = ty[cix*65 + jj]; s += v; s2 += v*v;
  }
  s += __shfl_xor(s, 1); s2 += __shfl_xor(s2, 1);
  s += __shfl_xor(s, 2); s2 += __shfl_xor(s2, 2);
  float mu = s * (1.f/192.f);
  float var = s2 * (1.f/192.f) - mu*mu;
  float rstd = rsqrtf(fmaxf(var, 0.f) + 1e-5f);
  long zbase = ((long)h*64 + jj)*Di;
  for (int cix = part*48; cix < part*48 + 48; ++cix){
    float zv = bfr(Zb[zbase + cix]);
    float g = zv / (1.f + __expf(-zv));
    float yn = (ty[cix*65 + jj] - mu) * rstd * ldv(lnw, cix) + ldv(lnb, cix);
    ty[cix*65 + jj] = yn * g;
  }
  __syncthreads();
  long ob = obase + ((long)b*Ln + h*64 + jj)*Cm;
  for (int o = part; o < Cm; o += 4){
    const T* wr = wo + (long)o*Di;
    float acc = 0.f;
    for (int cix = 0; cix < Di; cix += 4){
      float4 w4 = ldv4(wr, cix);
      acc += w4.x*ty[cix*65+jj] + w4.y*ty[(cix+1)*65+jj]
           + w4.z*ty[(cix+2)*65+jj] + w4.w*ty[(cix+3)*65+jj];
    }
    stv(out, ob + o, acc);
  }
}
__global__ __launch_bounds__(256) void k_out(const u16* ys, const u16* xcLD, const u16* Z,
                                             const void* Dsv, const void* lnw, const void* lnb,
                                             const void* wo, void* out, long obase, const int* flag){
  __shared__ float ty[Di*65];
  __shared__ float sDs[Di];
  if (*flag) out_body<float>(ys, xcLD, Z, (const float*)Dsv, (const float*)lnw, (const float*)lnb,
                             (const float*)wo, (float*)out, obase, ty, sDs);
  else       out_body<bf16 >(ys, xcLD, Z, (const bf16* )Dsv, (const bf16* )lnw, (const bf16* )lnb,
                             (const bf16* )wo, (bf16* )out, obase, ty, sDs);
}

extern "C" void kernel_launch(void* const* d_in, const int* in_sizes, int n_in,
                              void* d_out, int out_size, void* d_ws, size_t ws_size,
                              hipStream_t stream){
  const void* x    = d_in[0];
  const void* ipw  = d_in[1];
  const void* cw   = d_in[2];
  const void* cb   = d_in[3];
  const void* xpw  = d_in[4];
  const void* dtw  = d_in[5];
  const void* dtb  = d_in[6];
  const void* Alog = d_in[7];
  const void* Dsv  = d_in[8];
  const void* lnw  = d_in[9];
  const void* lnb  = d_in[10];
  const void* wo   = d_in[11];

  // per-batch bytes
  const size_t PLANE = (size_t)Ln*Di*2;             // 1.57 MB
  const size_t DTSB  = (size_t)Kn*Ln*6*2;           // 0.20 MB
  const size_t BCB   = (size_t)Kn*Ln*16*4;          // 1.05 MB
  const size_t YSB   = (size_t)Kn*Ln*Di*2;          // 6.29 MB
  const size_t SBB   = (size_t)Kn*Gc*Di*4;          // 0.10 MB
  const size_t QBB   = (size_t)Kn*Gc*Di*Ns*4;       // 1.57 MB
  const size_t HIB   = QBB;                         // 1.57 MB
  const size_t perB  = 4*PLANE + YSB + SBB + QBB + HIB;   // ~15.8 MB (dts/BC alias Xb)
  int Bc = 1;
  for (int c : {8, 4, 2, 1}) if (256 + (size_t)c*perB <= ws_size){ Bc = c; break; }
  int nch = 8 / Bc;

  char* base = (char*)d_ws;
  int*  flag = (int*)base;
  u16* Z     = (u16*)(base + 256);
  u16* xcLD  = Z     + (size_t)Bc*Ln*Di;
  u16* xcTLD = xcLD  + (size_t)Bc*Ln*Di;
  u16* Xb    = xcTLD + (size_t)Bc*Ln*Di;
  u16* ys    = Xb    + (size_t)Bc*Ln*Di;
  float* Sb  = (float*)(ys + (size_t)Bc*Kn*Ln*Di);
  float* Qb  = Sb + (size_t)Bc*Kn*Gc*Di;
  float* Hin = Qb + (size_t)Bc*Kn*Gc*Di*Ns;
  u16* dts   = Xb;                                   // alias (Xb dead after conv)
  u32* BC    = (u32*)(dts + (size_t)Bc*Kn*Ln*6);

  k_detect<<<1, 256, 0, stream>>>((const u16*)x, flag);

  for (int ch = 0; ch < nch; ++ch){
    long xoff = (long)ch*Bc*Ln*Cm;
    k_inproj <<<Bc*Ln/8,    384, 0, stream>>>(x, xoff, ipw, Xb, Z, flag);
    k_conv   <<<Bc*Hn,      256, 0, stream>>>(Xb, cw, cb, xcLD, xcTLD, flag);
    k_proj   <<<Bc*256,     256, 0, stream>>>(xcLD, xcTLD, xpw, dts, BC, flag);
    k_scan1  <<<Bc*Kn*Gc,   192, 0, stream>>>(xcLD, xcTLD, dts, BC, Alog, dtw, dtb, Sb, Qb, flag);
    k_fix    <<<Bc*Kn,      256, 0, stream>>>(Sb, Qb, Alog, Hin, flag);
    k_scan2  <<<Bc*Kn*Gc,   192, 0, stream>>>(xcLD, xcTLD, dts, BC, Alog, dtw, dtb, Hin, ys, flag);
    k_out    <<<Bc*Hn,      256, 0, stream>>>(ys, xcLD, Z, Dsv, lnw, lnb, wo, d_out, xoff, flag);
  }
}

// Round 10
// 1199.435 us; speedup vs baseline: 8.8808x; 1.0007x over previous
//
#include <hip/hip_runtime.h>
#include <hip/hip_bf16.h>

typedef __hip_bfloat16 bf16;
typedef unsigned short u16;
typedef unsigned int   u32;

constexpr int Hn=64, Wn=64, Cm=96, Ln=4096, Di=192, Kn=4, Ns=16, Rr=6;
constexpr int Gc=32, CH=128;   // 32 chunks of 128 positions

static __device__ __forceinline__ float ldv(const float* p, long i){ return p[i]; }
static __device__ __forceinline__ float ldv(const bf16*  p, long i){ return __bfloat162float(p[i]); }
static __device__ __forceinline__ void  stv(float* p, long i, float v){ p[i] = v; }
static __device__ __forceinline__ void  stv(bf16*  p, long i, float v){ p[i] = __float2bfloat16(v); }
static __device__ __forceinline__ float bfr(u16 u){ return __uint_as_float((u32)u << 16); }
static __device__ __forceinline__ u16   fbr(float f){ bf16 h = __float2bfloat16(f); return *(u16*)&h; }
static __device__ __forceinline__ float4 ldv4(const float* p, long i){ return *(const float4*)(p + i); }
static __device__ __forceinline__ float4 ldv4(const bf16* p, long i){
  ushort4 u = *(const ushort4*)(p + i);
  return make_float4(bfr(u.x), bfr(u.y), bfr(u.z), bfr(u.w));
}
static __device__ __forceinline__ float splus(float x){ return (x > 15.f) ? x : log1pf(__expf(x)); }

// ------------------------------------------------ dtype detector (f32 vs bf16)
__global__ void k_detect(const u16* x, int* flag){
  __shared__ int cnt;
  if (threadIdx.x == 0) cnt = 0;
  __syncthreads();
  int local = 0;
  for (int i = threadIdx.x; i < 8192; i += 256){
    int e = (x[i] >> 7) & 0xFF;
    if (e != 0 && (e < 90 || e > 164)) local++;
  }
  atomicAdd(&cnt, local);
  __syncthreads();
  if (threadIdx.x == 0) *flag = (cnt > 400) ? 1 : 0;   // 1 => float32 inputs
}

// ---------------------------------------------------------------- in_proj GEMM
template<typename T>
__device__ void inproj_body(const T* x, const T* w, u16* Xb, u16* Z){
  __shared__ float xs[8*96];
  int c = threadIdx.x;
  long p0 = (long)blockIdx.x * 8;
  for (int i = c; i < 768; i += 384) xs[i] = ldv(x, p0*96 + i);
  __syncthreads();
  float acc[8] = {0,0,0,0,0,0,0,0};
  for (int kk = 0; kk < 96; kk += 4){
    float4 wv = ldv4(w, (long)c*96 + kk);
    #pragma unroll
    for (int p = 0; p < 8; ++p)
      acc[p] += wv.x*xs[p*96+kk] + wv.y*xs[p*96+kk+1]
              + wv.z*xs[p*96+kk+2] + wv.w*xs[p*96+kk+3];
  }
  if (c < Di){
    #pragma unroll
    for (int p = 0; p < 8; ++p) Xb[(p0+p)*Di + c] = fbr(acc[p]);
  } else {
    int c2 = c - Di;
    #pragma unroll
    for (int p = 0; p < 8; ++p) Z[(p0+p)*Di + c2] = fbr(acc[p]);
  }
}
__global__ __launch_bounds__(384) void k_inproj(const void* x, long xoff, const void* w,
                                                u16* Xb, u16* Z, const int* flag){
  if (*flag) inproj_body<float>((const float*)x + xoff, (const float*)w, Xb, Z);
  else       inproj_body<bf16 >((const bf16* )x + xoff, (const bf16* )w, Xb, Z);
}

// ------------------- depthwise conv3x3 + SiLU -> xcLD (L,D) and xcTLD (Lt,D)
template<typename T>
__device__ void conv_body(const u16* Xb, const T* cw, const T* cb,
                          u16* xcLD, u16* xcTLD, float* wle, u16* tl){
  float* ble = wle + Di*9;
  int b = blockIdx.x >> 6, h = blockIdx.x & 63;
  for (int i = threadIdx.x; i < Di*9; i += 256) wle[i] = ldv(cw, i);
  for (int i = threadIdx.x; i < Di;   i += 256) ble[i] = ldv(cb, i);
  __syncthreads();
  const u16* Xbb = Xb + (long)b*Ln*Di;
  u16* xa = xcLD  + (long)b*Ln*Di;
  u16* xb = xcTLD + (long)b*Ln*Di;
  for (int i = threadIdx.x; i < Di*Wn; i += 256){
    int w = i / 192, d = i % 192;
    float acc = ble[d];
    #pragma unroll
    for (int dh = -1; dh <= 1; ++dh){
      int hh = h + dh; if (hh < 0 || hh > 63) continue;
      #pragma unroll
      for (int dw = -1; dw <= 1; ++dw){
        int ww = w + dw; if (ww < 0 || ww > 63) continue;
        acc += wle[d*9 + (dh+1)*3 + (dw+1)] * bfr(Xbb[(long)(hh*64+ww)*Di + d]);
      }
    }
    float sv = acc / (1.f + __expf(-acc));
    tl[d*66 + w] = fbr(sv);
  }
  __syncthreads();
  for (int i = threadIdx.x; i < Di*Wn; i += 256){
    int w = i / 192, d = i % 192;
    u16 v = tl[d*66 + w];
    xa[(long)(h*64 + w)*Di + d] = v;
    xb[(long)(w*64 + h)*Di + d] = v;
  }
}
__global__ __launch_bounds__(256) void k_conv(const u16* Xb, const void* cw, const void* cb,
                                              u16* xcLD, u16* xcTLD, const int* flag){
  __shared__ float wle[Di*9 + Di];
  __shared__ u16 tl[Di*66];
  if (*flag) conv_body<float>(Xb, (const float*)cw, (const float*)cb, xcLD, xcTLD, wle, tl);
  else       conv_body<bf16 >(Xb, (const bf16* )cw, (const bf16* )cb, xcLD, xcTLD, wle, tl);
}

// --------------------------------------------- x_proj (dts + packed B/C, scan order)
template<typename T>
__device__ void proj_body(const u16* xcLD, const u16* xcTLD, const T* xpw,
                          u16* dtsg, u32* BCg, float* xt){
  int blk = blockIdx.x;
  int tile = blk & 127; int s = (blk >> 7) & 1; int b = blk >> 8;
  int q0 = tile * 32;
  const u16* src = (s ? xcTLD : xcLD) + (long)b*Ln*Di;
  for (int i = threadIdx.x; i < Di*32; i += 256){
    int j = i / 192, d = i % 192;
    xt[d*33 + j] = bfr(src[(long)(q0+j)*Di + d]);
  }
  __syncthreads();
  for (int o = threadIdx.x; o < 2*22*32; o += 256){
    int j = o & 31; int t = (o >> 5) % 22; int kk = o / (22*32);
    int k = s + 2*kk;
    int q = q0 + j;
    int l = kk ? (Ln-1-q) : q;
    long base = (long)(b*Kn + k)*Ln + l;
    if (t < 6){
      const T* wr = xpw + ((long)k*38 + t)*Di;
      float acc = 0.f;
      for (int d2 = 0; d2 < Di; d2 += 4){
        float4 w4 = ldv4(wr, d2);
        acc += w4.x*xt[d2*33+j] + w4.y*xt[(d2+1)*33+j]
             + w4.z*xt[(d2+2)*33+j] + w4.w*xt[(d2+3)*33+j];
      }
      dtsg[base*6 + t] = fbr(acc);
    } else {
      int n = t - 6;
      const T* wB = xpw + ((long)k*38 + 6 + n)*Di;
      const T* wC = xpw + ((long)k*38 + 22 + n)*Di;
      float aB = 0.f, aC = 0.f;
      for (int d2 = 0; d2 < Di; d2 += 4){
        float4 b4 = ldv4(wB, d2);
        float4 c4 = ldv4(wC, d2);
        float x0 = xt[d2*33+j], x1 = xt[(d2+1)*33+j], x2 = xt[(d2+2)*33+j], x3 = xt[(d2+3)*33+j];
        aB += b4.x*x0 + b4.y*x1 + b4.z*x2 + b4.w*x3;
        aC += c4.x*x0 + c4.y*x1 + c4.z*x2 + c4.w*x3;
      }
      BCg[base*16 + n] = (u32)fbr(aB) | ((u32)fbr(aC) << 16);
    }
  }
}
__global__ __launch_bounds__(256) void k_proj(const u16* xcLD, const u16* xcTLD, const void* xpw,
                                              u16* dtsg, u32* BCg, const int* flag){
  __shared__ float xt[Di*33];
  if (*flag) proj_body<float>(xcLD, xcTLD, (const float*)xpw, dtsg, BCg, xt);
  else       proj_body<bf16 >(xcLD, xcTLD, (const bf16* )xpw, dtsg, BCg, xt);
}

// -------------------------------- scan pass 1: lane=d, h[16]+a[16] in registers
template<typename T>
__device__ void scan1_body(const u16* xcLD, const u16* xcTLD, const u16* dtsg, const u32* BCg,
                           const T* Alog, const T* dtw, const T* dtb,
                           float* Sb, float* Qb, float* sdt, float* sB, u16* su){
  int tid = threadIdx.x, blk = blockIdx.x;
  int g = blk & (Gc-1); int k = (blk >> 5) & 3; int b = blk >> 7;
  bool rev = k >= 2, odd = k & 1;
  int d = tid;
  const u16* src = (odd ? xcTLD : xcLD) + (long)b*Ln*Di;
  const u16* dlg = dtsg + (long)(b*Kn + k)*Ln*6;
  const u32* bcg = BCg + (long)(b*Kn + k)*Ln*16;
  float w[6], a[16], h[16];
  #pragma unroll
  for (int r = 0; r < 6; ++r) w[r] = ldv(dtw, ((long)k*Di + d)*6 + r);
  float bias = ldv(dtb, k*Di + d);
  #pragma unroll
  for (int n = 0; n < 16; ++n){ a[n] = -__expf(ldv(Alog, (long)d*16 + n)); h[n] = 0.f; }
  float S = 0.f;
  for (int t = 0; t < CH/64; ++t){
    int l0 = g*CH + t*64;
    __syncthreads();
    for (int i = tid; i < 384; i += 192){ int j = i/6, c = i - 6*j; sdt[j*8 + c] = bfr(dlg[(long)l0*6 + i]); }
    for (int i = tid; i < 1024; i += 192){ u32 v = bcg[(long)l0*16 + i]; sB[i] = bfr((u16)(v & 0xffff)); }
    for (int i = tid; i < 64*192; i += 192){
      int j = i / 192, dd = i % 192;
      int l = l0 + j; int pos = rev ? (Ln-1-l) : l;
      su[i] = src[(long)pos*Di + dd];
    }
    __syncthreads();
    for (int j = 0; j < 64; ++j){
      float dl = bias;
      #pragma unroll
      for (int r = 0; r < 6; ++r) dl += w[r]*sdt[j*8 + r];
      dl = splus(dl);
      float du = dl * bfr(su[j*192 + d]);
      float Bv[16];
      *(float4*)&Bv[0]  = *(const float4*)&sB[j*16];
      *(float4*)&Bv[4]  = *(const float4*)&sB[j*16+4];
      *(float4*)&Bv[8]  = *(const float4*)&sB[j*16+8];
      *(float4*)&Bv[12] = *(const float4*)&sB[j*16+12];
      #pragma unroll
      for (int n = 0; n < 16; ++n) h[n] = __expf(dl*a[n])*h[n] + du*Bv[n];
      S += dl;
    }
  }
  long ci = (long)(b*Kn + k)*Gc + g;
  Sb[ci*Di + d] = S;
  #pragma unroll
  for (int n = 0; n < 16; ++n) Qb[ci*3072 + (long)d*16 + n] = h[n];
}
__global__ __launch_bounds__(192,3) void k_scan1(const u16* xcLD, const u16* xcTLD, const u16* dtsg,
                                                 const u32* BCg, const void* Alog, const void* dtw,
                                                 const void* dtb, float* Sb, float* Qb, const int* flag){
  __shared__ float sdt[64*8];
  __shared__ float sB[64*16];
  __shared__ u16 su[64*192];
  if (*flag) scan1_body<float>(xcLD, xcTLD, dtsg, BCg, (const float*)Alog, (const float*)dtw,
                               (const float*)dtb, Sb, Qb, sdt, sB, su);
  else       scan1_body<bf16 >(xcLD, xcTLD, dtsg, BCg, (const bf16* )Alog, (const bf16* )dtw,
                               (const bf16* )dtb, Sb, Qb, sdt, sB, su);
}

// ---------------------- cross-chunk fixup: Hin[g] = scan of (exp(a*S), Q) over g
template<typename T>
__device__ void fix_body(const float* Sb, const float* Qb, const T* Alog, float* Hin){
  int bk = blockIdx.x;
  for (int s = threadIdx.x; s < 3072; s += 256){
    int d = s >> 4, n = s & 15;
    float a = -__expf(ldv(Alog, (long)d*16 + n));
    float h = 0.f;
    for (int g = 0; g < Gc; ++g){
      long ci = (long)bk*Gc + g;
      Hin[ci*3072 + s] = h;
      h = __expf(a * Sb[ci*Di + d]) * h + Qb[ci*3072 + s];
    }
  }
}
__global__ __launch_bounds__(256) void k_fix(const float* Sb, const float* Qb, const void* Alog,
                                             float* Hin, const int* flag){
  if (*flag) fix_body<float>(Sb, Qb, (const float*)Alog, Hin);
  else       fix_body<bf16 >(Sb, Qb, (const bf16* )Alog, Hin);
}

// -------------------------------- scan pass 2: rescan from Hin, emit ys (L,D)
template<typename T>
__device__ void scan2_body(const u16* xcLD, const u16* xcTLD, const u16* dtsg, const u32* BCg,
                           const T* Alog, const T* dtw, const T* dtb, const float* Hin,
                           u16* ys, float* sdt, float* sB, float* sC, u16* su){
  int tid = threadIdx.x, blk = blockIdx.x;
  int g = blk & (Gc-1); int k = (blk >> 5) & 3; int b = blk >> 7;
  bool rev = k >= 2, odd = k & 1;
  int d = tid;
  const u16* src = (odd ? xcTLD : xcLD) + (long)b*Ln*Di;
  const u16* dlg = dtsg + (long)(b*Kn + k)*Ln*6;
  const u32* bcg = BCg + (long)(b*Kn + k)*Ln*16;
  u16* yb = ys + (long)(b*Kn + k)*Ln*Di;
  float w[6], a[16], h[16];
  #pragma unroll
  for (int r = 0; r < 6; ++r) w[r] = ldv(dtw, ((long)k*Di + d)*6 + r);
  float bias = ldv(dtb, k*Di + d);
  long ci = (long)(b*Kn + k)*Gc + g;
  #pragma unroll
  for (int n = 0; n < 16; ++n){
    a[n] = -__expf(ldv(Alog, (long)d*16 + n));
    h[n] = Hin[ci*3072 + (long)d*16 + n];
  }
  for (int t = 0; t < CH/64; ++t){
    int l0 = g*CH + t*64;
    __syncthreads();
    for (int i = tid; i < 384; i += 192){ int j = i/6, c = i - 6*j; sdt[j*8 + c] = bfr(dlg[(long)l0*6 + i]); }
    for (int i = tid; i < 1024; i += 192){
      u32 v = bcg[(long)l0*16 + i];
      sB[i] = bfr((u16)(v & 0xffff));
      sC[i] = bfr((u16)(v >> 16));
    }
    for (int i = tid; i < 64*192; i += 192){
      int j = i / 192, dd = i % 192;
      int l = l0 + j; int pos = rev ? (Ln-1-l) : l;
      su[i] = src[(long)pos*Di + dd];
    }
    __syncthreads();
    for (int j = 0; j < 64; ++j){
      float dl = bias;
      #pragma unroll
      for (int r = 0; r < 6; ++r) dl += w[r]*sdt[j*8 + r];
      dl = splus(dl);
      float du = dl * bfr(su[j*192 + d]);
      float Bv[16], Cv[16];
      *(float4*)&Bv[0]  = *(const float4*)&sB[j*16];
      *(float4*)&Bv[4]  = *(const float4*)&sB[j*16+4];
      *(float4*)&Bv[8]  = *(const float4*)&sB[j*16+8];
      *(float4*)&Bv[12] = *(const float4*)&sB[j*16+12];
      *(float4*)&Cv[0]  = *(const float4*)&sC[j*16];
      *(float4*)&Cv[4]  = *(const float4*)&sC[j*16+4];
      *(float4*)&Cv[8]  = *(const float4*)&sC[j*16+8];
      *(float4*)&Cv[12] = *(const float4*)&sC[j*16+12];
      float y = 0.f;
      #pragma unroll
      for (int n = 0; n < 16; ++n){
        h[n] = __expf(dl*a[n])*h[n] + du*Bv[n];
        y += h[n]*Cv[n];
      }
      int l = l0 + j; int le = rev ? (Ln-1-l) : l;
      int sp = odd ? ((le & 63)*64 + (le >> 6)) : le;
      yb[(long)sp*Di + d] = fbr(y);
    }
  }
}
__global__ __launch_bounds__(192,3) void k_scan2(const u16* xcLD, const u16* xcTLD, const u16* dtsg,
                                                 const u32* BCg, const void* Alog, const void* dtw,
                                                 const void* dtb, const float* Hin, u16* ys,
                                                 const int* flag){
  __shared__ float sdt[64*8];
  __shared__ float sB[64*16];
  __shared__ float sC[64*16];
  __shared__ u16 su[64*192];
  if (*flag) scan2_body<float>(xcLD, xcTLD, dtsg, BCg, (const float*)Alog, (const float*)dtw,
                               (const float*)dtb, Hin, ys, sdt, sB, sC, su);
  else       scan2_body<bf16 >(xcLD, xcTLD, dtsg, BCg, (const bf16* )Alog, (const bf16* )dtw,
                               (const bf16* )dtb, Hin, ys, sdt, sB, sC, su);
}

// -------------------- merge + skip + LayerNorm + gate + out_proj
template<typename T>
__device__ void out_body(const u16* ys, const u16* xcLD, const u16* Z, const T* Dsv,
                         const T* lnw, const T* lnb, const T* wo, T* out, long obase,
                         float* ty, float* sDs){
  int b = blockIdx.x >> 6, h = blockIdx.x & 63;
  int tid = threadIdx.x;
  const u16* xcb = xcLD + (long)b*Ln*Di;
  const u16* Zb = Z + (long)b*Ln*Di;
  const u16* pl0 = ys + (long)(b*Kn + 0)*Ln*Di;
  const u16* pl1 = ys + (long)(b*Kn + 1)*Ln*Di;
  const u16* pl2 = ys + (long)(b*Kn + 2)*Ln*Di;
  const u16* pl3 = ys + (long)(b*Kn + 3)*Ln*Di;
  if (tid < Di)
    sDs[tid] = ldv(Dsv, tid) + ldv(Dsv, Di+tid) + ldv(Dsv, 2*Di+tid) + ldv(Dsv, 3*Di+tid);
  __syncthreads();
  for (int i = tid; i < Di*64; i += 256){
    int j = i / 192, d = i % 192;
    long ls = (long)(h*64 + j)*Di + d;
    long lt = (long)(j*64 + h)*Di + d;
    ty[d*65 + j] = bfr(pl0[ls]) + bfr(pl2[ls]) + bfr(pl1[lt]) + bfr(pl3[lt])
                 + sDs[d]*bfr(xcb[ls]);
  }
  __syncthreads();
  int jj = tid >> 2, part = tid & 3;
  float s = 0.f, s2 = 0.f;
  for (int cix = part*48; cix < part*48 + 48; ++cix){
    float v = ty[cix*65 + jj]; s += v; s2 += v*v;
  }
  s += __shfl_xor(s, 1); s2 += __shfl_xor(s2, 1);
  s += __shfl_xor(s, 2); s2 += __shfl_xor(s2, 2);
  float mu = s * (1.f/192.f);
  float var = s2 * (1.f/192.f) - mu*mu;
  float rstd = rsqrtf(fmaxf(var, 0.f) + 1e-5f);
  long zbase = ((long)h*64 + jj)*Di;
  for (int cix = part*48; cix < part*48 + 48; ++cix){
    float zv = bfr(Zb[zbase + cix]);
    float g = zv / (1.f + __expf(-zv));
    float yn = (ty[cix*65 + jj] - mu) * rstd * ldv(lnw, cix) + ldv(lnb, cix);
    ty[cix*65 + jj] = yn * g;
  }
  __syncthreads();
  long ob = obase + ((long)b*Ln + h*64 + jj)*Cm;
  for (int o = part; o < Cm; o += 4){
    const T* wr = wo + (long)o*Di;
    float acc = 0.f;
    for (int cix = 0; cix < Di; cix += 4){
      float4 w4 = ldv4(wr, cix);
      acc += w4.x*ty[cix*65+jj] + w4.y*ty[(cix+1)*65+jj]
           + w4.z*ty[(cix+2)*65+jj] + w4.w*ty[(cix+3)*65+jj];
    }
    stv(out, ob + o, acc);
  }
}
__global__ __launch_bounds__(256) void k_out(const u16* ys, const u16* xcLD, const u16* Z,
                                             const void* Dsv, const void* lnw, const void* lnb,
                                             const void* wo, void* out, long obase, const int* flag){
  __shared__ float ty[Di*65];
  __shared__ float sDs[Di];
  if (*flag) out_body<float>(ys, xcLD, Z, (const float*)Dsv, (const float*)lnw, (const float*)lnb,
                             (const float*)wo, (float*)out, obase, ty, sDs);
  else       out_body<bf16 >(ys, xcLD, Z, (const bf16* )Dsv, (const bf16* )lnw, (const bf16* )lnb,
                             (const bf16* )wo, (bf16* )out, obase, ty, sDs);
}

extern "C" void kernel_launch(void* const* d_in, const int* in_sizes, int n_in,
                              void* d_out, int out_size, void* d_ws, size_t ws_size,
                              hipStream_t stream){
  const void* x    = d_in[0];
  const void* ipw  = d_in[1];
  const void* cw   = d_in[2];
  const void* cb   = d_in[3];
  const void* xpw  = d_in[4];
  const void* dtw  = d_in[5];
  const void* dtb  = d_in[6];
  const void* Alog = d_in[7];
  const void* Dsv  = d_in[8];
  const void* lnw  = d_in[9];
  const void* lnb  = d_in[10];
  const void* wo   = d_in[11];

  // per-batch bytes
  const size_t PLANE = (size_t)Ln*Di*2;             // 1.57 MB
  const size_t DTSB  = (size_t)Kn*Ln*6*2;           // 0.20 MB
  const size_t BCB   = (size_t)Kn*Ln*16*4;          // 1.05 MB
  const size_t YSB   = (size_t)Kn*Ln*Di*2;          // 6.29 MB
  const size_t SBB   = (size_t)Kn*Gc*Di*4;          // 0.10 MB
  const size_t QBB   = (size_t)Kn*Gc*Di*Ns*4;       // 1.57 MB
  const size_t HIB   = QBB;                         // 1.57 MB
  const size_t perB  = 4*PLANE + YSB + SBB + QBB + HIB;   // ~15.8 MB (dts/BC alias Xb)
  int Bc = 1;
  for (int c : {8, 4, 2, 1}) if (256 + (size_t)c*perB <= ws_size){ Bc = c; break; }
  int nch = 8 / Bc;

  char* base = (char*)d_ws;
  int*  flag = (int*)base;
  u16* Z     = (u16*)(base + 256);
  u16* xcLD  = Z     + (size_t)Bc*Ln*Di;
  u16* xcTLD = xcLD  + (size_t)Bc*Ln*Di;
  u16* Xb    = xcTLD + (size_t)Bc*Ln*Di;
  u16* ys    = Xb    + (size_t)Bc*Ln*Di;
  float* Sb  = (float*)(ys + (size_t)Bc*Kn*Ln*Di);
  float* Qb  = Sb + (size_t)Bc*Kn*Gc*Di;
  float* Hin = Qb + (size_t)Bc*Kn*Gc*Di*Ns;
  u16* dts   = Xb;                                   // alias (Xb dead after conv)
  u32* BC    = (u32*)(dts + (size_t)Bc*Kn*Ln*6);

  k_detect<<<1, 256, 0, stream>>>((const u16*)x, flag);

  for (int ch = 0; ch < nch; ++ch){
    long xoff = (long)ch*Bc*Ln*Cm;
    k_inproj <<<Bc*Ln/8,    384, 0, stream>>>(x, xoff, ipw, Xb, Z, flag);
    k_conv   <<<Bc*Hn,      256, 0, stream>>>(Xb, cw, cb, xcLD, xcTLD, flag);
    k_proj   <<<Bc*256,     256, 0, stream>>>(xcLD, xcTLD, xpw, dts, BC, flag);
    k_scan1  <<<Bc*Kn*Gc,   192, 0, stream>>>(xcLD, xcTLD, dts, BC, Alog, dtw, dtb, Sb, Qb, flag);
    k_fix    <<<Bc*Kn,      256, 0, stream>>>(Sb, Qb, Alog, Hin, flag);
    k_scan2  <<<Bc*Kn*Gc,   192, 0, stream>>>(xcLD, xcTLD, dts, BC, Alog, dtw, dtb, Hin, ys, flag);
    k_out    <<<Bc*Hn,      256, 0, stream>>>(ys, xcLD, Z, Dsv, lnw, lnb, wo, d_out, xoff, flag);
  }
}

// Round 11
// 988.270 us; speedup vs baseline: 10.7784x; 1.2137x over previous
//
#include <hip/hip_runtime.h>
#include <hip/hip_bf16.h>

typedef __hip_bfloat16 bf16;
typedef unsigned short u16;
typedef unsigned int   u32;

constexpr int Hn=64, Wn=64, Cm=96, Ln=4096, Di=192, Kn=4, Ns=16, Rr=6;
constexpr int Gc=32, CH=128;   // 32 chunks of 128 positions

static __device__ __forceinline__ float ldv(const float* p, long i){ return p[i]; }
static __device__ __forceinline__ float ldv(const bf16*  p, long i){ return __bfloat162float(p[i]); }
static __device__ __forceinline__ void  stv(float* p, long i, float v){ p[i] = v; }
static __device__ __forceinline__ void  stv(bf16*  p, long i, float v){ p[i] = __float2bfloat16(v); }
static __device__ __forceinline__ float bfr(u16 u){ return __uint_as_float((u32)u << 16); }
static __device__ __forceinline__ u16   fbr(float f){ bf16 h = __float2bfloat16(f); return *(u16*)&h; }
static __device__ __forceinline__ float4 ldv4(const float* p, long i){ return *(const float4*)(p + i); }
static __device__ __forceinline__ float4 ldv4(const bf16* p, long i){
  ushort4 u = *(const ushort4*)(p + i);
  return make_float4(bfr(u.x), bfr(u.y), bfr(u.z), bfr(u.w));
}
static __device__ __forceinline__ float splus(float x){ return (x > 15.f) ? x : log1pf(__expf(x)); }

// ------------------------------------------------ dtype detector (f32 vs bf16)
__global__ void k_detect(const u16* x, int* flag){
  __shared__ int cnt;
  if (threadIdx.x == 0) cnt = 0;
  __syncthreads();
  int local = 0;
  for (int i = threadIdx.x; i < 8192; i += 256){
    int e = (x[i] >> 7) & 0xFF;
    if (e != 0 && (e < 90 || e > 164)) local++;
  }
  atomicAdd(&cnt, local);
  __syncthreads();
  if (threadIdx.x == 0) *flag = (cnt > 400) ? 1 : 0;   // 1 => float32 inputs
}

// ---------------------------------------------------------------- in_proj GEMM
template<typename T>
__device__ void inproj_body(const T* x, const T* w, u16* Xb, u16* Z){
  __shared__ float xs[8*96];
  int c = threadIdx.x;
  long p0 = (long)blockIdx.x * 8;
  for (int i = c; i < 768; i += 384) xs[i] = ldv(x, p0*96 + i);
  __syncthreads();
  float acc[8] = {0,0,0,0,0,0,0,0};
  for (int kk = 0; kk < 96; kk += 4){
    float4 wv = ldv4(w, (long)c*96 + kk);
    #pragma unroll
    for (int p = 0; p < 8; ++p)
      acc[p] += wv.x*xs[p*96+kk] + wv.y*xs[p*96+kk+1]
              + wv.z*xs[p*96+kk+2] + wv.w*xs[p*96+kk+3];
  }
  if (c < Di){
    #pragma unroll
    for (int p = 0; p < 8; ++p) Xb[(p0+p)*Di + c] = fbr(acc[p]);
  } else {
    int c2 = c - Di;
    #pragma unroll
    for (int p = 0; p < 8; ++p) Z[(p0+p)*Di + c2] = fbr(acc[p]);
  }
}
__global__ __launch_bounds__(384) void k_inproj(const void* x, long xoff, const void* w,
                                                u16* Xb, u16* Z, const int* flag){
  if (*flag) inproj_body<float>((const float*)x + xoff, (const float*)w, Xb, Z);
  else       inproj_body<bf16 >((const bf16* )x + xoff, (const bf16* )w, Xb, Z);
}

// ------------------- depthwise conv3x3 + SiLU -> xcLD (L,D) and xcTLD (Lt,D)
template<typename T>
__device__ void conv_body(const u16* Xb, const T* cw, const T* cb,
                          u16* xcLD, u16* xcTLD, float* wle, u16* tl){
  float* ble = wle + Di*9;
  int b = blockIdx.x >> 6, h = blockIdx.x & 63;
  for (int i = threadIdx.x; i < Di*9; i += 256) wle[i] = ldv(cw, i);
  for (int i = threadIdx.x; i < Di;   i += 256) ble[i] = ldv(cb, i);
  __syncthreads();
  const u16* Xbb = Xb + (long)b*Ln*Di;
  u16* xa = xcLD  + (long)b*Ln*Di;
  u16* xb = xcTLD + (long)b*Ln*Di;
  for (int i = threadIdx.x; i < Di*Wn; i += 256){
    int w = i / 192, d = i % 192;
    float acc = ble[d];
    #pragma unroll
    for (int dh = -1; dh <= 1; ++dh){
      int hh = h + dh; if (hh < 0 || hh > 63) continue;
      #pragma unroll
      for (int dw = -1; dw <= 1; ++dw){
        int ww = w + dw; if (ww < 0 || ww > 63) continue;
        acc += wle[d*9 + (dh+1)*3 + (dw+1)] * bfr(Xbb[(long)(hh*64+ww)*Di + d]);
      }
    }
    float sv = acc / (1.f + __expf(-acc));
    tl[d*66 + w] = fbr(sv);
  }
  __syncthreads();
  for (int i = threadIdx.x; i < Di*Wn; i += 256){
    int w = i / 192, d = i % 192;
    u16 v = tl[d*66 + w];
    xa[(long)(h*64 + w)*Di + d] = v;
    xb[(long)(w*64 + h)*Di + d] = v;
  }
}
__global__ __launch_bounds__(256) void k_conv(const u16* Xb, const void* cw, const void* cb,
                                              u16* xcLD, u16* xcTLD, const int* flag){
  __shared__ float wle[Di*9 + Di];
  __shared__ u16 tl[Di*66];
  if (*flag) conv_body<float>(Xb, (const float*)cw, (const float*)cb, xcLD, xcTLD, wle, tl);
  else       conv_body<bf16 >(Xb, (const bf16* )cw, (const bf16* )cb, xcLD, xcTLD, wle, tl);
}

// --------------------------------------------- x_proj (dts + packed B/C, scan order)
template<typename T>
__device__ void proj_body(const u16* xcLD, const u16* xcTLD, const T* xpw,
                          u16* dtsg, u32* BCg, float* xt){
  int blk = blockIdx.x;
  int tile = blk & 127; int s = (blk >> 7) & 1; int b = blk >> 8;
  int q0 = tile * 32;
  const u16* src = (s ? xcTLD : xcLD) + (long)b*Ln*Di;
  for (int i = threadIdx.x; i < Di*32; i += 256){
    int j = i / 192, d = i % 192;
    xt[d*33 + j] = bfr(src[(long)(q0+j)*Di + d]);
  }
  __syncthreads();
  for (int o = threadIdx.x; o < 2*22*32; o += 256){
    int j = o & 31; int t = (o >> 5) % 22; int kk = o / (22*32);
    int k = s + 2*kk;
    int q = q0 + j;
    int l = kk ? (Ln-1-q) : q;
    long base = (long)(b*Kn + k)*Ln + l;
    if (t < 6){
      const T* wr = xpw + ((long)k*38 + t)*Di;
      float acc = 0.f;
      for (int d2 = 0; d2 < Di; d2 += 4){
        float4 w4 = ldv4(wr, d2);
        acc += w4.x*xt[d2*33+j] + w4.y*xt[(d2+1)*33+j]
             + w4.z*xt[(d2+2)*33+j] + w4.w*xt[(d2+3)*33+j];
      }
      dtsg[base*6 + t] = fbr(acc);
    } else {
      int n = t - 6;
      const T* wB = xpw + ((long)k*38 + 6 + n)*Di;
      const T* wC = xpw + ((long)k*38 + 22 + n)*Di;
      float aB = 0.f, aC = 0.f;
      for (int d2 = 0; d2 < Di; d2 += 4){
        float4 b4 = ldv4(wB, d2);
        float4 c4 = ldv4(wC, d2);
        float x0 = xt[d2*33+j], x1 = xt[(d2+1)*33+j], x2 = xt[(d2+2)*33+j], x3 = xt[(d2+3)*33+j];
        aB += b4.x*x0 + b4.y*x1 + b4.z*x2 + b4.w*x3;
        aC += c4.x*x0 + c4.y*x1 + c4.z*x2 + c4.w*x3;
      }
      BCg[base*16 + n] = (u32)fbr(aB) | ((u32)fbr(aC) << 16);
    }
  }
}
__global__ __launch_bounds__(256) void k_proj(const u16* xcLD, const u16* xcTLD, const void* xpw,
                                              u16* dtsg, u32* BCg, const int* flag){
  __shared__ float xt[Di*33];
  if (*flag) proj_body<float>(xcLD, xcTLD, (const float*)xpw, dtsg, BCg, xt);
  else       proj_body<bf16 >(xcLD, xcTLD, (const bf16* )xpw, dtsg, BCg, xt);
}

// -------------------------------- scan pass 1: lane=d, h[16]+a[16] in registers
template<typename T>
__device__ void scan1_body(const u16* xcLD, const u16* xcTLD, const u16* dtsg, const u32* BCg,
                           const T* Alog, const T* dtw, const T* dtb,
                           float* Sb, float* Qb, float* sdt, float* sB, u16* su){
  int tid = threadIdx.x, blk = blockIdx.x;
  int g = blk & (Gc-1); int k = (blk >> 5) & 3; int b = blk >> 7;
  bool rev = k >= 2, odd = k & 1;
  int d = tid;
  const u16* src = (odd ? xcTLD : xcLD) + (long)b*Ln*Di;
  const u16* dlg = dtsg + (long)(b*Kn + k)*Ln*6;
  const u32* bcg = BCg + (long)(b*Kn + k)*Ln*16;
  float w[6], a[16], h[16];
  #pragma unroll
  for (int r = 0; r < 6; ++r) w[r] = ldv(dtw, ((long)k*Di + d)*6 + r);
  float bias = ldv(dtb, k*Di + d);
  #pragma unroll
  for (int n = 0; n < 16; ++n){ a[n] = -__expf(ldv(Alog, (long)d*16 + n)); h[n] = 0.f; }
  float S = 0.f;
  for (int t = 0; t < CH/64; ++t){
    int l0 = g*CH + t*64;
    __syncthreads();
    for (int i = tid; i < 384; i += 192){ int j = i/6, c = i - 6*j; sdt[j*8 + c] = bfr(dlg[(long)l0*6 + i]); }
    for (int i = tid; i < 1024; i += 192){ u32 v = bcg[(long)l0*16 + i]; sB[i] = bfr((u16)(v & 0xffff)); }
    for (int i = tid; i < 64*192; i += 192){
      int j = i / 192, dd = i % 192;
      int l = l0 + j; int pos = rev ? (Ln-1-l) : l;
      su[i] = src[(long)pos*Di + dd];
    }
    __syncthreads();
    for (int j = 0; j < 64; ++j){
      float dl = bias;
      #pragma unroll
      for (int r = 0; r < 6; ++r) dl += w[r]*sdt[j*8 + r];
      dl = splus(dl);
      float du = dl * bfr(su[j*192 + d]);
      float Bv[16];
      *(float4*)&Bv[0]  = *(const float4*)&sB[j*16];
      *(float4*)&Bv[4]  = *(const float4*)&sB[j*16+4];
      *(float4*)&Bv[8]  = *(const float4*)&sB[j*16+8];
      *(float4*)&Bv[12] = *(const float4*)&sB[j*16+12];
      #pragma unroll
      for (int n = 0; n < 16; ++n) h[n] = __expf(dl*a[n])*h[n] + du*Bv[n];
      S += dl;
    }
  }
  long ci = (long)(b*Kn + k)*Gc + g;
  Sb[ci*Di + d] = S;
  #pragma unroll
  for (int n = 0; n < 16; ++n) Qb[ci*3072 + (long)d*16 + n] = h[n];
}
__global__ __launch_bounds__(192,3) void k_scan1(const u16* xcLD, const u16* xcTLD, const u16* dtsg,
                                                 const u32* BCg, const void* Alog, const void* dtw,
                                                 const void* dtb, float* Sb, float* Qb, const int* flag){
  __shared__ float sdt[64*8];
  __shared__ float sB[64*16];
  __shared__ u16 su[64*192];
  if (*flag) scan1_body<float>(xcLD, xcTLD, dtsg, BCg, (const float*)Alog, (const float*)dtw,
                               (const float*)dtb, Sb, Qb, sdt, sB, su);
  else       scan1_body<bf16 >(xcLD, xcTLD, dtsg, BCg, (const bf16* )Alog, (const bf16* )dtw,
                               (const bf16* )dtb, Sb, Qb, sdt, sB, su);
}

// ---------------------- cross-chunk fixup: Hin[g] = scan of (exp(a*S), Q) over g
template<typename T>
__device__ void fix_body(const float* Sb, const float* Qb, const T* Alog, float* Hin){
  int bk = blockIdx.x;
  for (int s = threadIdx.x; s < 3072; s += 256){
    int d = s >> 4, n = s & 15;
    float a = -__expf(ldv(Alog, (long)d*16 + n));
    float h = 0.f;
    for (int g = 0; g < Gc; ++g){
      long ci = (long)bk*Gc + g;
      Hin[ci*3072 + s] = h;
      h = __expf(a * Sb[ci*Di + d]) * h + Qb[ci*3072 + s];
    }
  }
}
__global__ __launch_bounds__(256) void k_fix(const float* Sb, const float* Qb, const void* Alog,
                                             float* Hin, const int* flag){
  if (*flag) fix_body<float>(Sb, Qb, (const float*)Alog, Hin);
  else       fix_body<bf16 >(Sb, Qb, (const bf16* )Alog, Hin);
}

// -------------------------------- scan pass 2: rescan from Hin, emit ys (L,D)
template<typename T>
__device__ void scan2_body(const u16* xcLD, const u16* xcTLD, const u16* dtsg, const u32* BCg,
                           const T* Alog, const T* dtw, const T* dtb, const float* Hin,
                           u16* ys, float* sdt, float* sB, float* sC, u16* su){
  int tid = threadIdx.x, blk = blockIdx.x;
  int g = blk & (Gc-1); int k = (blk >> 5) & 3; int b = blk >> 7;
  bool rev = k >= 2, odd = k & 1;
  int d = tid;
  const u16* src = (odd ? xcTLD : xcLD) + (long)b*Ln*Di;
  const u16* dlg = dtsg + (long)(b*Kn + k)*Ln*6;
  const u32* bcg = BCg + (long)(b*Kn + k)*Ln*16;
  u16* yb = ys + (long)(b*Kn + k)*Ln*Di;
  float w[6], a[16], h[16];
  #pragma unroll
  for (int r = 0; r < 6; ++r) w[r] = ldv(dtw, ((long)k*Di + d)*6 + r);
  float bias = ldv(dtb, k*Di + d);
  long ci = (long)(b*Kn + k)*Gc + g;
  #pragma unroll
  for (int n = 0; n < 16; ++n){
    a[n] = -__expf(ldv(Alog, (long)d*16 + n));
    h[n] = Hin[ci*3072 + (long)d*16 + n];
  }
  for (int t = 0; t < CH/64; ++t){
    int l0 = g*CH + t*64;
    __syncthreads();
    for (int i = tid; i < 384; i += 192){ int j = i/6, c = i - 6*j; sdt[j*8 + c] = bfr(dlg[(long)l0*6 + i]); }
    for (int i = tid; i < 1024; i += 192){
      u32 v = bcg[(long)l0*16 + i];
      sB[i] = bfr((u16)(v & 0xffff));
      sC[i] = bfr((u16)(v >> 16));
    }
    for (int i = tid; i < 64*192; i += 192){
      int j = i / 192, dd = i % 192;
      int l = l0 + j; int pos = rev ? (Ln-1-l) : l;
      su[i] = src[(long)pos*Di + dd];
    }
    __syncthreads();
    for (int j = 0; j < 64; ++j){
      float dl = bias;
      #pragma unroll
      for (int r = 0; r < 6; ++r) dl += w[r]*sdt[j*8 + r];
      dl = splus(dl);
      float du = dl * bfr(su[j*192 + d]);
      float Bv[16], Cv[16];
      *(float4*)&Bv[0]  = *(const float4*)&sB[j*16];
      *(float4*)&Bv[4]  = *(const float4*)&sB[j*16+4];
      *(float4*)&Bv[8]  = *(const float4*)&sB[j*16+8];
      *(float4*)&Bv[12] = *(const float4*)&sB[j*16+12];
      *(float4*)&Cv[0]  = *(const float4*)&sC[j*16];
      *(float4*)&Cv[4]  = *(const float4*)&sC[j*16+4];
      *(float4*)&Cv[8]  = *(const float4*)&sC[j*16+8];
      *(float4*)&Cv[12] = *(const float4*)&sC[j*16+12];
      float y = 0.f;
      #pragma unroll
      for (int n = 0; n < 16; ++n){
        h[n] = __expf(dl*a[n])*h[n] + du*Bv[n];
        y += h[n]*Cv[n];
      }
      int l = l0 + j; int le = rev ? (Ln-1-l) : l;
      int sp = odd ? ((le & 63)*64 + (le >> 6)) : le;
      yb[(long)sp*Di + d] = fbr(y);
    }
  }
}
__global__ __launch_bounds__(192,3) void k_scan2(const u16* xcLD, const u16* xcTLD, const u16* dtsg,
                                                 const u32* BCg, const void* Alog, const void* dtw,
                                                 const void* dtb, const float* Hin, u16* ys,
                                                 const int* flag){
  __shared__ float sdt[64*8];
  __shared__ float sB[64*16];
  __shared__ float sC[64*16];
  __shared__ u16 su[64*192];
  if (*flag) scan2_body<float>(xcLD, xcTLD, dtsg, BCg, (const float*)Alog, (const float*)dtw,
                               (const float*)dtb, Hin, ys, sdt, sB, sC, su);
  else       scan2_body<bf16 >(xcLD, xcTLD, dtsg, BCg, (const bf16* )Alog, (const bf16* )dtw,
                               (const bf16* )dtb, Hin, ys, sdt, sB, sC, su);
}

// ------- merge + skip + LayerNorm + gate + out_proj (wo staged in LDS bf16)
// ty: bf16 [64 pos][196 pad] ; swo: bf16 [96 out][196 pad]
template<typename T>
__device__ void out_body(const u16* ys, const u16* xcLD, const u16* Z, const T* Dsv,
                         const T* lnw, const T* lnb, const T* wo, T* out, long obase,
                         u16* ty, u16* swo, float* sDs){
  int b = blockIdx.x >> 6, h = blockIdx.x & 63;
  int tid = threadIdx.x;
  const u16* xcb = xcLD + (long)b*Ln*Di;
  const u16* Zb = Z + (long)b*Ln*Di;
  const u16* pl0 = ys + (long)(b*Kn + 0)*Ln*Di;
  const u16* pl1 = ys + (long)(b*Kn + 1)*Ln*Di;
  const u16* pl2 = ys + (long)(b*Kn + 2)*Ln*Di;
  const u16* pl3 = ys + (long)(b*Kn + 3)*Ln*Di;
  if (tid < Di)
    sDs[tid] = ldv(Dsv, tid) + ldv(Dsv, Di+tid) + ldv(Dsv, 2*Di+tid) + ldv(Dsv, 3*Di+tid);
  __syncthreads();
  // stage wo -> LDS (bf16, padded rows)
  for (int i = tid; i < 96*192; i += 256){
    int r = i / 192, c = i % 192;
    swo[r*196 + c] = fbr(ldv(wo, i));
  }
  // merge + skip -> ty (position-major)
  for (int i = tid; i < Di*64; i += 256){
    int j = i / 192, d = i % 192;
    long ls = (long)(h*64 + j)*Di + d;
    long lt = (long)(j*64 + h)*Di + d;
    float v = bfr(pl0[ls]) + bfr(pl2[ls]) + bfr(pl1[lt]) + bfr(pl3[lt])
            + sDs[d]*bfr(xcb[ls]);
    ty[j*196 + d] = fbr(v);
  }
  __syncthreads();
  int jj = tid >> 2, part = tid & 3;
  float s = 0.f, s2 = 0.f;
  for (int cix = part*48; cix < part*48 + 48; ++cix){
    float v = bfr(ty[jj*196 + cix]); s += v; s2 += v*v;
  }
  s += __shfl_xor(s, 1); s2 += __shfl_xor(s2, 1);
  s += __shfl_xor(s, 2); s2 += __shfl_xor(s2, 2);
  float mu = s * (1.f/192.f);
  float var = s2 * (1.f/192.f) - mu*mu;
  float rstd = rsqrtf(fmaxf(var, 0.f) + 1e-5f);
  long zbase = ((long)h*64 + jj)*Di;
  for (int cix = part*48; cix < part*48 + 48; ++cix){
    float zv = bfr(Zb[zbase + cix]);
    float g = zv / (1.f + __expf(-zv));
    float yn = (bfr(ty[jj*196 + cix]) - mu) * rstd * ldv(lnw, cix) + ldv(lnb, cix);
    ty[jj*196 + cix] = fbr(yn * g);
  }
  __syncthreads();
  // out_proj: thread (p = position, q = output-quarter) computes 24 outputs
  int p = tid >> 2, q = tid & 3;
  float acc[24];
  #pragma unroll
  for (int oi = 0; oi < 24; ++oi) acc[oi] = 0.f;
  for (int kt = 0; kt < 6; ++kt){
    float xv[32];
    const u16* yr = &ty[p*196 + kt*32];
    #pragma unroll
    for (int j = 0; j < 32; j += 4){
      ushort4 u = *(const ushort4*)(yr + j);
      xv[j]=bfr(u.x); xv[j+1]=bfr(u.y); xv[j+2]=bfr(u.z); xv[j+3]=bfr(u.w);
    }
    #pragma unroll
    for (int oi = 0; oi < 24; ++oi){
      const u16* wr = &swo[(q*24 + oi)*196 + kt*32];
      float a2 = 0.f;
      #pragma unroll
      for (int j = 0; j < 32; j += 4){
        ushort4 wu = *(const ushort4*)(wr + j);
        a2 += bfr(wu.x)*xv[j] + bfr(wu.y)*xv[j+1] + bfr(wu.z)*xv[j+2] + bfr(wu.w)*xv[j+3];
      }
      acc[oi] += a2;
    }
  }
  long ob = obase + ((long)b*Ln + h*64 + p)*Cm + q*24;
  #pragma unroll
  for (int oi = 0; oi < 24; ++oi) stv(out, ob + oi, acc[oi]);
}
__global__ __launch_bounds__(256) void k_out(const u16* ys, const u16* xcLD, const u16* Z,
                                             const void* Dsv, const void* lnw, const void* lnb,
                                             const void* wo, void* out, long obase, const int* flag){
  __shared__ u16 ty[64*196];      // 25088 B
  __shared__ u16 swo[96*196];     // 37632 B
  __shared__ float sDs[Di];       //   768 B  -> total 63488 B
  if (*flag) out_body<float>(ys, xcLD, Z, (const float*)Dsv, (const float*)lnw, (const float*)lnb,
                             (const float*)wo, (float*)out, obase, ty, swo, sDs);
  else       out_body<bf16 >(ys, xcLD, Z, (const bf16* )Dsv, (const bf16* )lnw, (const bf16* )lnb,
                             (const bf16* )wo, (bf16* )out, obase, ty, swo, sDs);
}

extern "C" void kernel_launch(void* const* d_in, const int* in_sizes, int n_in,
                              void* d_out, int out_size, void* d_ws, size_t ws_size,
                              hipStream_t stream){
  const void* x    = d_in[0];
  const void* ipw  = d_in[1];
  const void* cw   = d_in[2];
  const void* cb   = d_in[3];
  const void* xpw  = d_in[4];
  const void* dtw  = d_in[5];
  const void* dtb  = d_in[6];
  const void* Alog = d_in[7];
  const void* Dsv  = d_in[8];
  const void* lnw  = d_in[9];
  const void* lnb  = d_in[10];
  const void* wo   = d_in[11];

  // per-batch bytes
  const size_t PLANE = (size_t)Ln*Di*2;             // 1.57 MB
  const size_t YSB   = (size_t)Kn*Ln*Di*2;          // 6.29 MB
  const size_t SBB   = (size_t)Kn*Gc*Di*4;          // 0.10 MB
  const size_t QBB   = (size_t)Kn*Gc*Di*Ns*4;       // 1.57 MB
  const size_t HIB   = QBB;                         // 1.57 MB
  const size_t perB  = 4*PLANE + YSB + SBB + QBB + HIB;   // ~15.8 MB (dts/BC alias Xb)
  int Bc = 1;
  for (int c : {8, 4, 2, 1}) if (256 + (size_t)c*perB <= ws_size){ Bc = c; break; }
  int nch = 8 / Bc;

  char* base = (char*)d_ws;
  int*  flag = (int*)base;
  u16* Z     = (u16*)(base + 256);
  u16* xcLD  = Z     + (size_t)Bc*Ln*Di;
  u16* xcTLD = xcLD  + (size_t)Bc*Ln*Di;
  u16* Xb    = xcTLD + (size_t)Bc*Ln*Di;
  u16* ys    = Xb    + (size_t)Bc*Ln*Di;
  float* Sb  = (float*)(ys + (size_t)Bc*Kn*Ln*Di);
  float* Qb  = Sb + (size_t)Bc*Kn*Gc*Di;
  float* Hin = Qb + (size_t)Bc*Kn*Gc*Di*Ns;
  u16* dts   = Xb;                                   // alias (Xb dead after conv)
  u32* BC    = (u32*)(dts + (size_t)Bc*Kn*Ln*6);

  k_detect<<<1, 256, 0, stream>>>((const u16*)x, flag);

  for (int ch = 0; ch < nch; ++ch){
    long xoff = (long)ch*Bc*Ln*Cm;
    k_inproj <<<Bc*Ln/8,    384, 0, stream>>>(x, xoff, ipw, Xb, Z, flag);
    k_conv   <<<Bc*Hn,      256, 0, stream>>>(Xb, cw, cb, xcLD, xcTLD, flag);
    k_proj   <<<Bc*256,     256, 0, stream>>>(xcLD, xcTLD, xpw, dts, BC, flag);
    k_scan1  <<<Bc*Kn*Gc,   192, 0, stream>>>(xcLD, xcTLD, dts, BC, Alog, dtw, dtb, Sb, Qb, flag);
    k_fix    <<<Bc*Kn,      256, 0, stream>>>(Sb, Qb, Alog, Hin, flag);
    k_scan2  <<<Bc*Kn*Gc,   192, 0, stream>>>(xcLD, xcTLD, dts, BC, Alog, dtw, dtb, Hin, ys, flag);
    k_out    <<<Bc*Hn,      256, 0, stream>>>(ys, xcLD, Z, Dsv, lnw, lnb, wo, d_out, xoff, flag);
  }
}

// Round 12
// 764.463 us; speedup vs baseline: 13.9339x; 1.2928x over previous
//
#include <hip/hip_runtime.h>
#include <hip/hip_bf16.h>

typedef __hip_bfloat16 bf16;
typedef unsigned short u16;
typedef unsigned int   u32;

constexpr int Hn=64, Wn=64, Cm=96, Ln=4096, Di=192, Kn=4, Ns=16, Rr=6;
constexpr int Gc=32, CH=128;   // 32 chunks of 128 positions

static __device__ __forceinline__ float ldv(const float* p, long i){ return p[i]; }
static __device__ __forceinline__ float ldv(const bf16*  p, long i){ return __bfloat162float(p[i]); }
static __device__ __forceinline__ void  stv(float* p, long i, float v){ p[i] = v; }
static __device__ __forceinline__ void  stv(bf16*  p, long i, float v){ p[i] = __float2bfloat16(v); }
static __device__ __forceinline__ float bfr(u16 u){ return __uint_as_float((u32)u << 16); }
static __device__ __forceinline__ u16   fbr(float f){ bf16 h = __float2bfloat16(f); return *(u16*)&h; }
static __device__ __forceinline__ float4 ldv4(const float* p, long i){ return *(const float4*)(p + i); }
static __device__ __forceinline__ float4 ldv4(const bf16* p, long i){
  ushort4 u = *(const ushort4*)(p + i);
  return make_float4(bfr(u.x), bfr(u.y), bfr(u.z), bfr(u.w));
}
static __device__ __forceinline__ float splus(float x){ return (x > 15.f) ? x : log1pf(__expf(x)); }

// ---------------- dtype detector (f32 vs bf16) + Alog structure detector
__global__ void k_detect(const u16* x, const void* Alog, int* flag, int* flag2){
  __shared__ int cnt, cnt2;
  if (threadIdx.x == 0){ cnt = 0; cnt2 = 0; }
  __syncthreads();
  int local = 0;
  for (int i = threadIdx.x; i < 8192; i += 256){
    int e = (x[i] >> 7) & 0xFF;
    if (e != 0 && (e < 90 || e > 164)) local++;
  }
  atomicAdd(&cnt, local);
  __syncthreads();
  int f = (cnt > 400) ? 1 : 0;          // 1 => float32 inputs
  // verify Alog[d][n] == log(n+1) (true for this model family; tol rejects bf16)
  int bad = 0;
  for (int i = threadIdx.x; i < Di*Ns; i += 256){
    float v = f ? ((const float*)Alog)[i] : bfr(((const u16*)Alog)[i]);
    float ex = __logf((float)((i & 15) + 1));
    if (fabsf(v - ex) > 1e-5f) bad++;
  }
  atomicAdd(&cnt2, bad);
  __syncthreads();
  if (threadIdx.x == 0){ *flag = f; *flag2 = (cnt2 == 0) ? 1 : 0; }
}

// ---------------------------------------------------------------- in_proj GEMM
template<typename T>
__device__ void inproj_body(const T* x, const T* w, u16* Xb, u16* Z){
  __shared__ float xs[8*96];
  int c = threadIdx.x;
  long p0 = (long)blockIdx.x * 8;
  for (int i = c; i < 768; i += 384) xs[i] = ldv(x, p0*96 + i);
  __syncthreads();
  float acc[8] = {0,0,0,0,0,0,0,0};
  for (int kk = 0; kk < 96; kk += 4){
    float4 wv = ldv4(w, (long)c*96 + kk);
    #pragma unroll
    for (int p = 0; p < 8; ++p)
      acc[p] += wv.x*xs[p*96+kk] + wv.y*xs[p*96+kk+1]
              + wv.z*xs[p*96+kk+2] + wv.w*xs[p*96+kk+3];
  }
  if (c < Di){
    #pragma unroll
    for (int p = 0; p < 8; ++p) Xb[(p0+p)*Di + c] = fbr(acc[p]);
  } else {
    int c2 = c - Di;
    #pragma unroll
    for (int p = 0; p < 8; ++p) Z[(p0+p)*Di + c2] = fbr(acc[p]);
  }
}
__global__ __launch_bounds__(384) void k_inproj(const void* x, long xoff, const void* w,
                                                u16* Xb, u16* Z, const int* flag){
  if (*flag) inproj_body<float>((const float*)x + xoff, (const float*)w, Xb, Z);
  else       inproj_body<bf16 >((const bf16* )x + xoff, (const bf16* )w, Xb, Z);
}

// ------------------- depthwise conv3x3 + SiLU -> xcLD (L,D) and xcTLD (Lt,D)
template<typename T>
__device__ void conv_body(const u16* Xb, const T* cw, const T* cb,
                          u16* xcLD, u16* xcTLD, float* wle, u16* tl){
  float* ble = wle + Di*9;
  int b = blockIdx.x >> 6, h = blockIdx.x & 63;
  for (int i = threadIdx.x; i < Di*9; i += 256) wle[i] = ldv(cw, i);
  for (int i = threadIdx.x; i < Di;   i += 256) ble[i] = ldv(cb, i);
  __syncthreads();
  const u16* Xbb = Xb + (long)b*Ln*Di;
  u16* xa = xcLD  + (long)b*Ln*Di;
  u16* xb = xcTLD + (long)b*Ln*Di;
  for (int i = threadIdx.x; i < Di*Wn; i += 256){
    int w = i / 192, d = i % 192;
    float acc = ble[d];
    #pragma unroll
    for (int dh = -1; dh <= 1; ++dh){
      int hh = h + dh; if (hh < 0 || hh > 63) continue;
      #pragma unroll
      for (int dw = -1; dw <= 1; ++dw){
        int ww = w + dw; if (ww < 0 || ww > 63) continue;
        acc += wle[d*9 + (dh+1)*3 + (dw+1)] * bfr(Xbb[(long)(hh*64+ww)*Di + d]);
      }
    }
    float sv = acc / (1.f + __expf(-acc));
    tl[d*66 + w] = fbr(sv);
  }
  __syncthreads();
  for (int i = threadIdx.x; i < Di*Wn; i += 256){
    int w = i / 192, d = i % 192;
    u16 v = tl[d*66 + w];
    xa[(long)(h*64 + w)*Di + d] = v;
    xb[(long)(w*64 + h)*Di + d] = v;
  }
}
__global__ __launch_bounds__(256) void k_conv(const u16* Xb, const void* cw, const void* cb,
                                              u16* xcLD, u16* xcTLD, const int* flag){
  __shared__ float wle[Di*9 + Di];
  __shared__ u16 tl[Di*66];
  if (*flag) conv_body<float>(Xb, (const float*)cw, (const float*)cb, xcLD, xcTLD, wle, tl);
  else       conv_body<bf16 >(Xb, (const bf16* )cw, (const bf16* )cb, xcLD, xcTLD, wle, tl);
}

// --------------------------------------------- x_proj (dts + packed B/C, scan order)
template<typename T>
__device__ void proj_body(const u16* xcLD, const u16* xcTLD, const T* xpw,
                          u16* dtsg, u32* BCg, float* xt){
  int blk = blockIdx.x;
  int tile = blk & 127; int s = (blk >> 7) & 1; int b = blk >> 8;
  int q0 = tile * 32;
  const u16* src = (s ? xcTLD : xcLD) + (long)b*Ln*Di;
  for (int i = threadIdx.x; i < Di*32; i += 256){
    int j = i / 192, d = i % 192;
    xt[d*33 + j] = bfr(src[(long)(q0+j)*Di + d]);
  }
  __syncthreads();
  for (int o = threadIdx.x; o < 2*22*32; o += 256){
    int j = o & 31; int t = (o >> 5) % 22; int kk = o / (22*32);
    int k = s + 2*kk;
    int q = q0 + j;
    int l = kk ? (Ln-1-q) : q;
    long base = (long)(b*Kn + k)*Ln + l;
    if (t < 6){
      const T* wr = xpw + ((long)k*38 + t)*Di;
      float acc = 0.f;
      for (int d2 = 0; d2 < Di; d2 += 4){
        float4 w4 = ldv4(wr, d2);
        acc += w4.x*xt[d2*33+j] + w4.y*xt[(d2+1)*33+j]
             + w4.z*xt[(d2+2)*33+j] + w4.w*xt[(d2+3)*33+j];
      }
      dtsg[base*6 + t] = fbr(acc);
    } else {
      int n = t - 6;
      const T* wB = xpw + ((long)k*38 + 6 + n)*Di;
      const T* wC = xpw + ((long)k*38 + 22 + n)*Di;
      float aB = 0.f, aC = 0.f;
      for (int d2 = 0; d2 < Di; d2 += 4){
        float4 b4 = ldv4(wB, d2);
        float4 c4 = ldv4(wC, d2);
        float x0 = xt[d2*33+j], x1 = xt[(d2+1)*33+j], x2 = xt[(d2+2)*33+j], x3 = xt[(d2+3)*33+j];
        aB += b4.x*x0 + b4.y*x1 + b4.z*x2 + b4.w*x3;
        aC += c4.x*x0 + c4.y*x1 + c4.z*x2 + c4.w*x3;
      }
      BCg[base*16 + n] = (u32)fbr(aB) | ((u32)fbr(aC) << 16);
    }
  }
}
__global__ __launch_bounds__(256) void k_proj(const u16* xcLD, const u16* xcTLD, const void* xpw,
                                              u16* dtsg, u32* BCg, const int* flag){
  __shared__ float xt[Di*33];
  if (*flag) proj_body<float>(xcLD, xcTLD, (const float*)xpw, dtsg, BCg, xt);
  else       proj_body<bf16 >(xcLD, xcTLD, (const bf16* )xpw, dtsg, BCg, xt);
}

// softplus + decay pair: dl = softplus(xv), rr = exp(-dl) (reuses exp(xv))
static __device__ __forceinline__ void sp_decay(float xv, float& dl, float& rr){
  if (xv > 15.f){ dl = xv; rr = __expf(-xv); }
  else {
    float o = 1.f + __expf(xv);
    dl = __logf(o);
    rr = __builtin_amdgcn_rcpf(o);
  }
}

// -------------------------------- scan pass 1: lane=d, h[16]+a[16] in registers
template<typename T>
__device__ void scan1_body(const u16* xcLD, const u16* xcTLD, const u16* dtsg, const u32* BCg,
                           const T* Alog, const T* dtw, const T* dtb,
                           float* Sb, float* Qb, float* sdt, float* sB, u16* su, int fastA){
  int tid = threadIdx.x, blk = blockIdx.x;
  int g = blk & (Gc-1); int k = (blk >> 5) & 3; int b = blk >> 7;
  bool rev = k >= 2, odd = k & 1;
  int d = tid;
  const u16* src = (odd ? xcTLD : xcLD) + (long)b*Ln*Di;
  const u16* dlg = dtsg + (long)(b*Kn + k)*Ln*6;
  const u32* bcg = BCg + (long)(b*Kn + k)*Ln*16;
  float w[6], a[16], h[16];
  #pragma unroll
  for (int r = 0; r < 6; ++r) w[r] = ldv(dtw, ((long)k*Di + d)*6 + r);
  float bias = ldv(dtb, k*Di + d);
  #pragma unroll
  for (int n = 0; n < 16; ++n){ a[n] = -__expf(ldv(Alog, (long)d*16 + n)); h[n] = 0.f; }
  float S = 0.f;
  for (int t = 0; t < CH/64; ++t){
    int l0 = g*CH + t*64;
    __syncthreads();
    for (int i = tid; i < 384; i += 192){ int j = i/6, c = i - 6*j; sdt[j*8 + c] = bfr(dlg[(long)l0*6 + i]); }
    for (int i = tid; i < 1024; i += 192){ u32 v = bcg[(long)l0*16 + i]; sB[i] = bfr((u16)(v & 0xffff)); }
    for (int i = tid; i < 64*192; i += 192){
      int j = i / 192, dd = i % 192;
      int l = l0 + j; int pos = rev ? (Ln-1-l) : l;
      su[i] = src[(long)pos*Di + dd];
    }
    __syncthreads();
    if (fastA){
      for (int j = 0; j < 64; ++j){
        float xv = bias;
        #pragma unroll
        for (int r = 0; r < 6; ++r) xv += w[r]*sdt[j*8 + r];
        float dl, rr; sp_decay(xv, dl, rr);
        float du = dl * bfr(su[j*192 + d]);
        float Bv[16];
        *(float4*)&Bv[0]  = *(const float4*)&sB[j*16];
        *(float4*)&Bv[4]  = *(const float4*)&sB[j*16+4];
        *(float4*)&Bv[8]  = *(const float4*)&sB[j*16+8];
        *(float4*)&Bv[12] = *(const float4*)&sB[j*16+12];
        float p = rr;
        #pragma unroll
        for (int n = 0; n < 16; ++n){ h[n] = p*h[n] + du*Bv[n]; p *= rr; }
        S += dl;
      }
    } else {
      for (int j = 0; j < 64; ++j){
        float dl = bias;
        #pragma unroll
        for (int r = 0; r < 6; ++r) dl += w[r]*sdt[j*8 + r];
        dl = splus(dl);
        float du = dl * bfr(su[j*192 + d]);
        float Bv[16];
        *(float4*)&Bv[0]  = *(const float4*)&sB[j*16];
        *(float4*)&Bv[4]  = *(const float4*)&sB[j*16+4];
        *(float4*)&Bv[8]  = *(const float4*)&sB[j*16+8];
        *(float4*)&Bv[12] = *(const float4*)&sB[j*16+12];
        #pragma unroll
        for (int n = 0; n < 16; ++n) h[n] = __expf(dl*a[n])*h[n] + du*Bv[n];
        S += dl;
      }
    }
  }
  long ci = (long)(b*Kn + k)*Gc + g;
  Sb[ci*Di + d] = S;
  #pragma unroll
  for (int n = 0; n < 16; ++n) Qb[ci*3072 + (long)d*16 + n] = h[n];
}
__global__ __launch_bounds__(192,3) void k_scan1(const u16* xcLD, const u16* xcTLD, const u16* dtsg,
                                                 const u32* BCg, const void* Alog, const void* dtw,
                                                 const void* dtb, float* Sb, float* Qb,
                                                 const int* flag, const int* flag2){
  __shared__ float sdt[64*8];
  __shared__ float sB[64*16];
  __shared__ u16 su[64*192];
  int f2 = *flag2;
  if (*flag) scan1_body<float>(xcLD, xcTLD, dtsg, BCg, (const float*)Alog, (const float*)dtw,
                               (const float*)dtb, Sb, Qb, sdt, sB, su, f2);
  else       scan1_body<bf16 >(xcLD, xcTLD, dtsg, BCg, (const bf16* )Alog, (const bf16* )dtw,
                               (const bf16* )dtb, Sb, Qb, sdt, sB, su, f2);
}

// ---------------------- cross-chunk fixup: Hin[g] = scan of (exp(a*S), Q) over g
template<typename T>
__device__ void fix_body(const float* Sb, const float* Qb, const T* Alog, float* Hin){
  int bk = blockIdx.x;
  for (int s = threadIdx.x; s < 3072; s += 256){
    int d = s >> 4, n = s & 15;
    float a = -__expf(ldv(Alog, (long)d*16 + n));
    float h = 0.f;
    for (int g = 0; g < Gc; ++g){
      long ci = (long)bk*Gc + g;
      Hin[ci*3072 + s] = h;
      h = __expf(a * Sb[ci*Di + d]) * h + Qb[ci*3072 + s];
    }
  }
}
__global__ __launch_bounds__(256) void k_fix(const float* Sb, const float* Qb, const void* Alog,
                                             float* Hin, const int* flag){
  if (*flag) fix_body<float>(Sb, Qb, (const float*)Alog, Hin);
  else       fix_body<bf16 >(Sb, Qb, (const bf16* )Alog, Hin);
}

// -------------------------------- scan pass 2: rescan from Hin, emit ys (L,D)
template<typename T>
__device__ void scan2_body(const u16* xcLD, const u16* xcTLD, const u16* dtsg, const u32* BCg,
                           const T* Alog, const T* dtw, const T* dtb, const float* Hin,
                           u16* ys, float* sdt, float* sB, float* sC, u16* su, int fastA){
  int tid = threadIdx.x, blk = blockIdx.x;
  int g = blk & (Gc-1); int k = (blk >> 5) & 3; int b = blk >> 7;
  bool rev = k >= 2, odd = k & 1;
  int d = tid;
  const u16* src = (odd ? xcTLD : xcLD) + (long)b*Ln*Di;
  const u16* dlg = dtsg + (long)(b*Kn + k)*Ln*6;
  const u32* bcg = BCg + (long)(b*Kn + k)*Ln*16;
  u16* yb = ys + (long)(b*Kn + k)*Ln*Di;
  float w[6], a[16], h[16];
  #pragma unroll
  for (int r = 0; r < 6; ++r) w[r] = ldv(dtw, ((long)k*Di + d)*6 + r);
  float bias = ldv(dtb, k*Di + d);
  long ci = (long)(b*Kn + k)*Gc + g;
  #pragma unroll
  for (int n = 0; n < 16; ++n){
    a[n] = -__expf(ldv(Alog, (long)d*16 + n));
    h[n] = Hin[ci*3072 + (long)d*16 + n];
  }
  for (int t = 0; t < CH/64; ++t){
    int l0 = g*CH + t*64;
    __syncthreads();
    for (int i = tid; i < 384; i += 192){ int j = i/6, c = i - 6*j; sdt[j*8 + c] = bfr(dlg[(long)l0*6 + i]); }
    for (int i = tid; i < 1024; i += 192){
      u32 v = bcg[(long)l0*16 + i];
      sB[i] = bfr((u16)(v & 0xffff));
      sC[i] = bfr((u16)(v >> 16));
    }
    for (int i = tid; i < 64*192; i += 192){
      int j = i / 192, dd = i % 192;
      int l = l0 + j; int pos = rev ? (Ln-1-l) : l;
      su[i] = src[(long)pos*Di + dd];
    }
    __syncthreads();
    if (fastA){
      for (int j = 0; j < 64; ++j){
        float xv = bias;
        #pragma unroll
        for (int r = 0; r < 6; ++r) xv += w[r]*sdt[j*8 + r];
        float dl, rr; sp_decay(xv, dl, rr);
        float du = dl * bfr(su[j*192 + d]);
        float Bv[16], Cv[16];
        *(float4*)&Bv[0]  = *(const float4*)&sB[j*16];
        *(float4*)&Bv[4]  = *(const float4*)&sB[j*16+4];
        *(float4*)&Bv[8]  = *(const float4*)&sB[j*16+8];
        *(float4*)&Bv[12] = *(const float4*)&sB[j*16+12];
        *(float4*)&Cv[0]  = *(const float4*)&sC[j*16];
        *(float4*)&Cv[4]  = *(const float4*)&sC[j*16+4];
        *(float4*)&Cv[8]  = *(const float4*)&sC[j*16+8];
        *(float4*)&Cv[12] = *(const float4*)&sC[j*16+12];
        float y = 0.f;
        float p = rr;
        #pragma unroll
        for (int n = 0; n < 16; ++n){
          h[n] = p*h[n] + du*Bv[n];
          y += h[n]*Cv[n];
          p *= rr;
        }
        int l = l0 + j; int le = rev ? (Ln-1-l) : l;
        int sp = odd ? ((le & 63)*64 + (le >> 6)) : le;
        yb[(long)sp*Di + d] = fbr(y);
      }
    } else {
      for (int j = 0; j < 64; ++j){
        float dl = bias;
        #pragma unroll
        for (int r = 0; r < 6; ++r) dl += w[r]*sdt[j*8 + r];
        dl = splus(dl);
        float du = dl * bfr(su[j*192 + d]);
        float Bv[16], Cv[16];
        *(float4*)&Bv[0]  = *(const float4*)&sB[j*16];
        *(float4*)&Bv[4]  = *(const float4*)&sB[j*16+4];
        *(float4*)&Bv[8]  = *(const float4*)&sB[j*16+8];
        *(float4*)&Bv[12] = *(const float4*)&sB[j*16+12];
        *(float4*)&Cv[0]  = *(const float4*)&sC[j*16];
        *(float4*)&Cv[4]  = *(const float4*)&sC[j*16+4];
        *(float4*)&Cv[8]  = *(const float4*)&sC[j*16+8];
        *(float4*)&Cv[12] = *(const float4*)&sC[j*16+12];
        float y = 0.f;
        #pragma unroll
        for (int n = 0; n < 16; ++n){
          h[n] = __expf(dl*a[n])*h[n] + du*Bv[n];
          y += h[n]*Cv[n];
        }
        int l = l0 + j; int le = rev ? (Ln-1-l) : l;
        int sp = odd ? ((le & 63)*64 + (le >> 6)) : le;
        yb[(long)sp*Di + d] = fbr(y);
      }
    }
  }
}
__global__ __launch_bounds__(192,3) void k_scan2(const u16* xcLD, const u16* xcTLD, const u16* dtsg,
                                                 const u32* BCg, const void* Alog, const void* dtw,
                                                 const void* dtb, const float* Hin, u16* ys,
                                                 const int* flag, const int* flag2){
  __shared__ float sdt[64*8];
  __shared__ float sB[64*16];
  __shared__ float sC[64*16];
  __shared__ u16 su[64*192];
  int f2 = *flag2;
  if (*flag) scan2_body<float>(xcLD, xcTLD, dtsg, BCg, (const float*)Alog, (const float*)dtw,
                               (const float*)dtb, Hin, ys, sdt, sB, sC, su, f2);
  else       scan2_body<bf16 >(xcLD, xcTLD, dtsg, BCg, (const bf16* )Alog, (const bf16* )dtw,
                               (const bf16* )dtb, Hin, ys, sdt, sB, sC, su, f2);
}

// ------- merge + skip + LayerNorm + gate + out_proj (wo staged in LDS bf16)
template<typename T>
__device__ void out_body(const u16* ys, const u16* xcLD, const u16* Z, const T* Dsv,
                         const T* lnw, const T* lnb, const T* wo, T* out, long obase,
                         u16* ty, u16* swo, float* sDs){
  int b = blockIdx.x >> 6, h = blockIdx.x & 63;
  int tid = threadIdx.x;
  const u16* xcb = xcLD + (long)b*Ln*Di;
  const u16* Zb = Z + (long)b*Ln*Di;
  const u16* pl0 = ys + (long)(b*Kn + 0)*Ln*Di;
  const u16* pl1 = ys + (long)(b*Kn + 1)*Ln*Di;
  const u16* pl2 = ys + (long)(b*Kn + 2)*Ln*Di;
  const u16* pl3 = ys + (long)(b*Kn + 3)*Ln*Di;
  if (tid < Di)
    sDs[tid] = ldv(Dsv, tid) + ldv(Dsv, Di+tid) + ldv(Dsv, 2*Di+tid) + ldv(Dsv, 3*Di+tid);
  __syncthreads();
  for (int i = tid; i < 96*192; i += 256){
    int r = i / 192, c = i % 192;
    swo[r*196 + c] = fbr(ldv(wo, i));
  }
  for (int i = tid; i < Di*64; i += 256){
    int j = i / 192, d = i % 192;
    long ls = (long)(h*64 + j)*Di + d;
    long lt = (long)(j*64 + h)*Di + d;
    float v = bfr(pl0[ls]) + bfr(pl2[ls]) + bfr(pl1[lt]) + bfr(pl3[lt])
            + sDs[d]*bfr(xcb[ls]);
    ty[j*196 + d] = fbr(v);
  }
  __syncthreads();
  int jj = tid >> 2, part = tid & 3;
  float s = 0.f, s2 = 0.f;
  for (int cix = part*48; cix < part*48 + 48; ++cix){
    float v = bfr(ty[jj*196 + cix]); s += v; s2 += v*v;
  }
  s += __shfl_xor(s, 1); s2 += __shfl_xor(s2, 1);
  s += __shfl_xor(s, 2); s2 += __shfl_xor(s2, 2);
  float mu = s * (1.f/192.f);
  float var = s2 * (1.f/192.f) - mu*mu;
  float rstd = rsqrtf(fmaxf(var, 0.f) + 1e-5f);
  long zbase = ((long)h*64 + jj)*Di;
  for (int cix = part*48; cix < part*48 + 48; ++cix){
    float zv = bfr(Zb[zbase + cix]);
    float g = zv / (1.f + __expf(-zv));
    float yn = (bfr(ty[jj*196 + cix]) - mu) * rstd * ldv(lnw, cix) + ldv(lnb, cix);
    ty[jj*196 + cix] = fbr(yn * g);
  }
  __syncthreads();
  int p = tid >> 2, q = tid & 3;
  float acc[24];
  #pragma unroll
  for (int oi = 0; oi < 24; ++oi) acc[oi] = 0.f;
  for (int kt = 0; kt < 6; ++kt){
    float xv[32];
    const u16* yr = &ty[p*196 + kt*32];
    #pragma unroll
    for (int j = 0; j < 32; j += 4){
      ushort4 u = *(const ushort4*)(yr + j);
      xv[j]=bfr(u.x); xv[j+1]=bfr(u.y); xv[j+2]=bfr(u.z); xv[j+3]=bfr(u.w);
    }
    #pragma unroll
    for (int oi = 0; oi < 24; ++oi){
      const u16* wr = &swo[(q*24 + oi)*196 + kt*32];
      float a2 = 0.f;
      #pragma unroll
      for (int j = 0; j < 32; j += 4){
        ushort4 wu = *(const ushort4*)(wr + j);
        a2 += bfr(wu.x)*xv[j] + bfr(wu.y)*xv[j+1] + bfr(wu.z)*xv[j+2] + bfr(wu.w)*xv[j+3];
      }
      acc[oi] += a2;
    }
  }
  long ob = obase + ((long)b*Ln + h*64 + p)*Cm + q*24;
  #pragma unroll
  for (int oi = 0; oi < 24; ++oi) stv(out, ob + oi, acc[oi]);
}
__global__ __launch_bounds__(256) void k_out(const u16* ys, const u16* xcLD, const u16* Z,
                                             const void* Dsv, const void* lnw, const void* lnb,
                                             const void* wo, void* out, long obase, const int* flag){
  __shared__ u16 ty[64*196];
  __shared__ u16 swo[96*196];
  __shared__ float sDs[Di];
  if (*flag) out_body<float>(ys, xcLD, Z, (const float*)Dsv, (const float*)lnw, (const float*)lnb,
                             (const float*)wo, (float*)out, obase, ty, swo, sDs);
  else       out_body<bf16 >(ys, xcLD, Z, (const bf16* )Dsv, (const bf16* )lnw, (const bf16* )lnb,
                             (const bf16* )wo, (bf16* )out, obase, ty, swo, sDs);
}

extern "C" void kernel_launch(void* const* d_in, const int* in_sizes, int n_in,
                              void* d_out, int out_size, void* d_ws, size_t ws_size,
                              hipStream_t stream){
  const void* x    = d_in[0];
  const void* ipw  = d_in[1];
  const void* cw   = d_in[2];
  const void* cb   = d_in[3];
  const void* xpw  = d_in[4];
  const void* dtw  = d_in[5];
  const void* dtb  = d_in[6];
  const void* Alog = d_in[7];
  const void* Dsv  = d_in[8];
  const void* lnw  = d_in[9];
  const void* lnb  = d_in[10];
  const void* wo   = d_in[11];

  const size_t PLANE = (size_t)Ln*Di*2;
  const size_t YSB   = (size_t)Kn*Ln*Di*2;
  const size_t SBB   = (size_t)Kn*Gc*Di*4;
  const size_t QBB   = (size_t)Kn*Gc*Di*Ns*4;
  const size_t HIB   = QBB;
  const size_t perB  = 4*PLANE + YSB + SBB + QBB + HIB;
  int Bc = 1;
  for (int c : {8, 4, 2, 1}) if (256 + (size_t)c*perB <= ws_size){ Bc = c; break; }
  int nch = 8 / Bc;

  char* base = (char*)d_ws;
  int*  flag  = (int*)base;
  int*  flag2 = (int*)(base + 8);
  u16* Z     = (u16*)(base + 256);
  u16* xcLD  = Z     + (size_t)Bc*Ln*Di;
  u16* xcTLD = xcLD  + (size_t)Bc*Ln*Di;
  u16* Xb    = xcTLD + (size_t)Bc*Ln*Di;
  u16* ys    = Xb    + (size_t)Bc*Ln*Di;
  float* Sb  = (float*)(ys + (size_t)Bc*Kn*Ln*Di);
  float* Qb  = Sb + (size_t)Bc*Kn*Gc*Di;
  float* Hin = Qb + (size_t)Bc*Kn*Gc*Di*Ns;
  u16* dts   = Xb;
  u32* BC    = (u32*)(dts + (size_t)Bc*Kn*Ln*6);

  k_detect<<<1, 256, 0, stream>>>((const u16*)x, Alog, flag, flag2);

  for (int ch = 0; ch < nch; ++ch){
    long xoff = (long)ch*Bc*Ln*Cm;
    k_inproj <<<Bc*Ln/8,    384, 0, stream>>>(x, xoff, ipw, Xb, Z, flag);
    k_conv   <<<Bc*Hn,      256, 0, stream>>>(Xb, cw, cb, xcLD, xcTLD, flag);
    k_proj   <<<Bc*256,     256, 0, stream>>>(xcLD, xcTLD, xpw, dts, BC, flag);
    k_scan1  <<<Bc*Kn*Gc,   192, 0, stream>>>(xcLD, xcTLD, dts, BC, Alog, dtw, dtb, Sb, Qb, flag, flag2);
    k_fix    <<<Bc*Kn,      256, 0, stream>>>(Sb, Qb, Alog, Hin, flag);
    k_scan2  <<<Bc*Kn*Gc,   192, 0, stream>>>(xcLD, xcTLD, dts, BC, Alog, dtw, dtb, Hin, ys, flag, flag2);
    k_out    <<<Bc*Hn,      256, 0, stream>>>(ys, xcLD, Z, Dsv, lnw, lnb, wo, d_out, xoff, flag);
  }
}